// Round 1
// baseline (551.768 us; speedup 1.0000x reference)
//
#include <hip/hip_runtime.h>
#include <hip/hip_bf16.h>
#include <math.h>

// ---------------- problem constants ----------------
constexpr int Bn = 2, Hn = 12, BHn = 24;
constexpr int Nn = 2048, Dn = 64;
constexpr int Mn = 266, MPn = 272;          // M padded to 272 (zero-filled)
constexpr int E3n = 192, DHn = 128, Tn = 128;
constexpr int Cn = 128, NCn = 16;           // chunking

#define DNRM 0.35355339059327373f   // 64^-0.25
#define KEPS 1e-3f
#define DEPS 1e-6f
#define LNEPS 1e-5f

// ---------------- ws layout (bytes) ----------------
static const size_t OFF_QF   = 0;            // bf16 [BH][N][MP]   26,738,688
static const size_t OFF_KF   = 26738688;     // bf16 [BH][N][MP]
static const size_t OFF_QK   = 53477376;     // bf16 [BH][NC][C][C] 12,582,912
static const size_t OFF_D    = 66060288;     // f32  [BH][N]          196,608
static const size_t OFF_KPRE = 66256896;     // f32  [BH][NC][MP]     417,792
static const size_t OFF_S    = 66674688;     // bf16 [BH][NC][MP][E3] 40,108,032
static const size_t WS_NEED  = 106782720;

// ---------------- helpers ----------------
__device__ inline float u2f(unsigned int u) {
  union { float f; unsigned int i; } c; c.i = u << 16; return c.f;
}
__device__ inline unsigned short f2u(float x) {
  __hip_bfloat16 h = __float2bfloat16(x);
  unsigned short u; __builtin_memcpy(&u, &h, 2); return u;
}
__device__ inline void unpack8(uint4 v, float* a) {
  a[0] = u2f(v.x & 0xffffu); a[1] = u2f(v.x >> 16);
  a[2] = u2f(v.y & 0xffffu); a[3] = u2f(v.y >> 16);
  a[4] = u2f(v.z & 0xffffu); a[5] = u2f(v.z >> 16);
  a[6] = u2f(v.w & 0xffffu); a[7] = u2f(v.w >> 16);
}

// ================= K1: performer features ==================
// qf/kf[row][m] = relu(dn * x[row]·proj[m]) + eps   (bf16, m>=266 -> 0)
__global__ __launch_bounds__(256) void k_features(
    const float* __restrict__ q, const float* __restrict__ k,
    const float* __restrict__ proj,
    unsigned short* __restrict__ qf, unsigned short* __restrict__ kf) {
  __shared__ float xt[64][68];   // [k][row]
  __shared__ float pt[64][68];   // [k][col]
  const float* x = (blockIdx.y == 0) ? q : k;
  unsigned short* outp = (blockIdx.y == 0) ? qf : kf;
  int tid = threadIdx.x;
  int r0 = blockIdx.x * 64;
  for (int idx = tid * 4; idx < 4096; idx += 1024) {
    int row = idx >> 6, kk = idx & 63;
    float4 v = *(const float4*)(x + (size_t)(r0 + row) * Dn + kk);
    xt[kk][row] = v.x; xt[kk+1][row] = v.y; xt[kk+2][row] = v.z; xt[kk+3][row] = v.w;
  }
  int tx = tid & 15, ty = tid >> 4;
  int rr = ty * 4, cc = tx * 4;
  for (int ct = 0; ct < 5; ++ct) {
    int c0 = ct * 64;
    __syncthreads();
    for (int idx = tid * 4; idx < 4096; idx += 1024) {
      int col = idx >> 6, kk = idx & 63;
      int p = c0 + col;
      float4 v = make_float4(0.f, 0.f, 0.f, 0.f);
      if (p < Mn) v = *(const float4*)(proj + (size_t)p * Dn + kk);
      pt[kk][col] = v.x; pt[kk+1][col] = v.y; pt[kk+2][col] = v.z; pt[kk+3][col] = v.w;
    }
    __syncthreads();
    float acc[4][4] = {};
    #pragma unroll 8
    for (int kk = 0; kk < 64; ++kk) {
      float4 av = *(const float4*)&xt[kk][rr];
      float4 bv = *(const float4*)&pt[kk][cc];
      float a[4] = {av.x, av.y, av.z, av.w};
      float b[4] = {bv.x, bv.y, bv.z, bv.w};
      #pragma unroll
      for (int i = 0; i < 4; ++i)
        #pragma unroll
        for (int j = 0; j < 4; ++j) acc[i][j] += a[i] * b[j];
    }
    int m0w = c0 + cc;
    if (m0w < MPn) {
      #pragma unroll
      for (int r = 0; r < 4; ++r) {
        int row = r0 + rr + r;
        ushort4 o;
        unsigned short* op = (unsigned short*)&o;
        #pragma unroll
        for (int s = 0; s < 4; ++s) {
          int m = m0w + s;
          float val = 0.f;
          if (m < Mn) val = fmaxf(acc[r][s] * DNRM, 0.f) + KEPS;
          op[s] = f2u(val);
        }
        *(ushort4*)(outp + (size_t)row * MPn + m0w) = o;
      }
    }
  }
}

// ================= K2a: per-chunk kf column sums ==================
__global__ __launch_bounds__(256) void k_ksum(const unsigned short* __restrict__ kf,
                                              float* __restrict__ kpre) {
  int blk = blockIdx.x; int bh = blk >> 4, c = blk & 15;
  int tid = threadIdx.x;
  for (int m = tid; m < MPn; m += 256) {
    const unsigned short* base = kf + ((size_t)bh * Nn + (size_t)c * Cn) * MPn + m;
    float s = 0.f;
    #pragma unroll 8
    for (int j = 0; j < Cn; ++j) s += u2f(base[(size_t)j * MPn]);
    kpre[((size_t)bh * NCn + c) * MPn + m] = s;
  }
}

// ================= K2b: in-place exclusive prefix over chunks ==================
__global__ __launch_bounds__(256) void k_kprefix(float* __restrict__ kpre) {
  int bh = blockIdx.x; int tid = threadIdx.x;
  for (int m = tid; m < MPn; m += 256) {
    float v[NCn];
    #pragma unroll
    for (int c = 0; c < NCn; ++c) v[c] = kpre[((size_t)bh * NCn + c) * MPn + m];
    float acc = 0.f;
    #pragma unroll
    for (int c = 0; c < NCn; ++c) {
      kpre[((size_t)bh * NCn + c) * MPn + m] = acc;
      acc += v[c];
    }
  }
}

// ================= K3: masked qk + denominator ==================
__global__ __launch_bounds__(256) void k_qk(const unsigned short* __restrict__ qf,
                                            const unsigned short* __restrict__ kf,
                                            const float* __restrict__ kpre,
                                            unsigned short* __restrict__ qk,
                                            float* __restrict__ dden) {
  __shared__ unsigned short qt[16][128];   // [m-local][i]
  __shared__ unsigned short kt[16][128];   // [m-local][j]
  __shared__ float kp[MPn];
  __shared__ float red[128][17];
  int blk = blockIdx.x;
  int bh = blk >> 4, c = blk & 15;
  int tid = threadIdx.x;
  int tx = tid & 15, ty = tid >> 4;
  int li = tid & 127, mg = tid >> 7;
  size_t qbase = ((size_t)bh * Nn + (size_t)c * Cn) * MPn;
  for (int m = tid; m < MPn; m += 256) kp[m] = kpre[((size_t)bh * NCn + c) * MPn + m];
  float acc[8][8] = {};
  for (int mt = 0; mt < MPn; mt += 16) {
    __syncthreads();
    {
      uint4 v = *(const uint4*)(qf + qbase + (size_t)li * MPn + mt + mg * 8);
      unsigned short tmp[8]; __builtin_memcpy(tmp, &v, 16);
      #pragma unroll
      for (int t = 0; t < 8; ++t) qt[mg * 8 + t][li] = tmp[t];
      uint4 w = *(const uint4*)(kf + qbase + (size_t)li * MPn + mt + mg * 8);
      __builtin_memcpy(tmp, &w, 16);
      #pragma unroll
      for (int t = 0; t < 8; ++t) kt[mg * 8 + t][li] = tmp[t];
    }
    __syncthreads();
    #pragma unroll 4
    for (int mm = 0; mm < 16; ++mm) {
      uint4 av = *(const uint4*)&qt[mm][ty * 8];
      uint4 bv = *(const uint4*)&kt[mm][tx * 8];
      float a[8], b[8];
      unpack8(av, a); unpack8(bv, b);
      #pragma unroll
      for (int r = 0; r < 8; ++r)
        #pragma unroll
        for (int s = 0; s < 8; ++s) acc[r][s] += a[r] * b[s];
    }
  }
  int i0 = ty * 8, j0 = tx * 8;
  #pragma unroll
  for (int r = 0; r < 8; ++r) {
    float s = 0.f;
    #pragma unroll
    for (int t = 0; t < 8; ++t) {
      if (j0 + t > i0 + r) acc[r][t] = 0.f;
      s += acc[r][t];
    }
    red[i0 + r][tx] = s;
  }
  __syncthreads();
  if (tid < 128) {
    float s = 0.f;
    #pragma unroll
    for (int t = 0; t < 16; ++t) s += red[tid][t];
    float dot = 0.f, qs = 0.f;
    const unsigned short* qrow = qf + qbase + (size_t)tid * MPn;
    for (int m = 0; m < MPn; m += 8) {
      uint4 v = *(const uint4*)(qrow + m);
      float a[8]; unpack8(v, a);
      #pragma unroll
      for (int t = 0; t < 8; ++t) { dot += a[t] * kp[m + t]; qs += a[t]; }
    }
    dden[(size_t)bh * Nn + (size_t)c * Cn + tid] = s + dot + DEPS * qs;
  }
  size_t qkbase = (size_t)blk * (Cn * Cn);
  #pragma unroll
  for (int r = 0; r < 8; ++r) {
    ushort4 o0, o1;
    unsigned short* p0 = (unsigned short*)&o0;
    unsigned short* p1 = (unsigned short*)&o1;
    #pragma unroll
    for (int t = 0; t < 4; ++t) { p0[t] = f2u(acc[r][t]); p1[t] = f2u(acc[r][t + 4]); }
    unsigned short* dst = qk + qkbase + (size_t)(i0 + r) * Cn + j0;
    *(ushort4*)dst = o0;
    *(ushort4*)(dst + 4) = o1;
  }
}

// ================= K4: per-chunk S_c = kf_c^T @ v_c ==================
__global__ __launch_bounds__(256) void k_schunk(const unsigned short* __restrict__ kf,
                                                const float* __restrict__ v3,
                                                unsigned short* __restrict__ S) {
  __shared__ float vt[128][64];            // [j][e-local]
  __shared__ unsigned short kft[128][64];  // [j][m-local]
  int blk = blockIdx.x, ey = blockIdx.y;
  int bh = blk >> 4, c = blk & 15;
  int e0 = ey * 64;
  int tid = threadIdx.x, tx = tid & 15, ty = tid >> 4;
  size_t vbase = ((size_t)bh * Nn + (size_t)c * Cn) * E3n + e0;
  for (int idx = tid * 4; idx < 8192; idx += 1024) {
    int j = idx >> 6, e = idx & 63;
    *(float4*)&vt[j][e] = *(const float4*)(v3 + vbase + (size_t)j * E3n + e);
  }
  size_t kbase = ((size_t)bh * Nn + (size_t)c * Cn) * MPn;
  size_t Sbase = (size_t)blk * MPn * E3n;
  for (int mb = 0; mb < 5; ++mb) {
    int m0 = mb * 64;
    __syncthreads();
    for (int idx = tid * 8; idx < 8192; idx += 2048) {
      int j = idx >> 6, ml = idx & 63;
      int m = m0 + ml;
      uint4 v = make_uint4(0u, 0u, 0u, 0u);
      if (m < MPn) v = *(const uint4*)(kf + kbase + (size_t)j * MPn + m);
      *(uint4*)&kft[j][ml] = v;
    }
    __syncthreads();
    float acc[4][4] = {};
    for (int j = 0; j < 128; ++j) {
      ushort4 kv = *(const ushort4*)&kft[j][ty * 4];
      float4 bv = *(const float4*)&vt[j][tx * 4];
      float a[4] = {u2f(kv.x), u2f(kv.y), u2f(kv.z), u2f(kv.w)};
      float b[4] = {bv.x, bv.y, bv.z, bv.w};
      #pragma unroll
      for (int r = 0; r < 4; ++r)
        #pragma unroll
        for (int s = 0; s < 4; ++s) acc[r][s] += a[r] * b[s];
    }
    #pragma unroll
    for (int r = 0; r < 4; ++r) {
      int m = m0 + ty * 4 + r;
      if (m < MPn) {
        ushort4 o;
        unsigned short* op = (unsigned short*)&o;
        #pragma unroll
        for (int s = 0; s < 4; ++s) op[s] = f2u(acc[r][s]);
        *(ushort4*)(S + Sbase + (size_t)m * E3n + e0 + tx * 4) = o;
      }
    }
  }
}

// ================= K5: in-place exclusive prefix of S over chunks ==================
__global__ __launch_bounds__(256) void k_sprefix(unsigned short* __restrict__ S) {
  int bh = blockIdx.x / 51, sub = blockIdx.x % 51;
  int idx4 = sub * 256 + threadIdx.x;          // 51*256 == MPn*E3n/4 exactly
  size_t off = (size_t)idx4 * 4;
  ushort4 v[NCn];
  #pragma unroll
  for (int c = 0; c < NCn; ++c)
    v[c] = *(const ushort4*)(S + ((size_t)(bh * NCn + c)) * MPn * E3n + off);
  float a0 = 0.f, a1 = 0.f, a2 = 0.f, a3 = 0.f;
  #pragma unroll
  for (int c = 0; c < NCn; ++c) {
    ushort4 o;
    unsigned short* op = (unsigned short*)&o;
    op[0] = f2u(a0); op[1] = f2u(a1); op[2] = f2u(a2); op[3] = f2u(a3);
    *(ushort4*)(S + ((size_t)(bh * NCn + c)) * MPn * E3n + off) = o;
    a0 += u2f(v[c].x); a1 += u2f(v[c].y); a2 += u2f(v[c].z); a3 += u2f(v[c].w);
  }
}

// ================= K6: ctx = (qf@S_pre + qk@v) / d ==================
__global__ __launch_bounds__(256) void k_ctx(const unsigned short* __restrict__ qf,
                                             const unsigned short* __restrict__ qk,
                                             const unsigned short* __restrict__ S,
                                             const float* __restrict__ v3,
                                             const float* __restrict__ dden,
                                             float* __restrict__ ctx) {
  __shared__ unsigned short qt[16][128];
  __shared__ unsigned short st[16][64];
  __shared__ unsigned short qkt[16][128];
  __shared__ float vt[16][64];
  int blk = blockIdx.x, ey = blockIdx.y;
  int bh = blk >> 4, c = blk & 15;
  int e0 = ey * 64;
  int tid = threadIdx.x, tx = tid & 15, ty = tid >> 4;
  int li = tid & 127, g = tid >> 7;
  size_t qbase = ((size_t)bh * Nn + (size_t)c * Cn) * MPn;
  size_t Sbase = (size_t)blk * MPn * E3n;
  float acc[8][4] = {};
  for (int mt = 0; mt < MPn; mt += 16) {
    __syncthreads();
    {
      uint4 v = *(const uint4*)(qf + qbase + (size_t)li * MPn + mt + g * 8);
      unsigned short tmp[8]; __builtin_memcpy(tmp, &v, 16);
      #pragma unroll
      for (int t = 0; t < 8; ++t) qt[g * 8 + t][li] = tmp[t];
    }
    {
      int idx = tid * 4;
      int mm = idx >> 6, el = idx & 63;
      ushort4 v = *(const ushort4*)(S + Sbase + (size_t)(mt + mm) * E3n + e0 + el);
      *(ushort4*)&st[mm][el] = v;
    }
    __syncthreads();
    #pragma unroll 4
    for (int mm = 0; mm < 16; ++mm) {
      uint4 av = *(const uint4*)&qt[mm][ty * 8];
      float a[8]; unpack8(av, a);
      ushort4 bv = *(const ushort4*)&st[mm][tx * 4];
      float b[4] = {u2f(bv.x), u2f(bv.y), u2f(bv.z), u2f(bv.w)};
      #pragma unroll
      for (int r = 0; r < 8; ++r)
        #pragma unroll
        for (int s = 0; s < 4; ++s) acc[r][s] += a[r] * b[s];
    }
  }
  size_t qkbase = (size_t)blk * (Cn * Cn);
  size_t vbase = ((size_t)bh * Nn + (size_t)c * Cn) * E3n + e0;
  for (int jt = 0; jt < Cn; jt += 16) {
    __syncthreads();
    {
      uint4 v = *(const uint4*)(qk + qkbase + (size_t)li * Cn + jt + g * 8);
      unsigned short tmp[8]; __builtin_memcpy(tmp, &v, 16);
      #pragma unroll
      for (int t = 0; t < 8; ++t) qkt[g * 8 + t][li] = tmp[t];
    }
    {
      int idx = tid * 4;
      int jj = idx >> 6, el = idx & 63;
      *(float4*)&vt[jj][el] = *(const float4*)(v3 + vbase + (size_t)(jt + jj) * E3n + el);
    }
    __syncthreads();
    #pragma unroll 4
    for (int jj = 0; jj < 16; ++jj) {
      uint4 av = *(const uint4*)&qkt[jj][ty * 8];
      float a[8]; unpack8(av, a);
      float4 bv = *(const float4*)&vt[jj][tx * 4];
      float b[4] = {bv.x, bv.y, bv.z, bv.w};
      #pragma unroll
      for (int r = 0; r < 8; ++r)
        #pragma unroll
        for (int s = 0; s < 4; ++s) acc[r][s] += a[r] * b[s];
    }
  }
  size_t rbase = (size_t)bh * Nn + (size_t)c * Cn;
  #pragma unroll
  for (int r = 0; r < 8; ++r) {
    int i = ty * 8 + r;
    float inv = 1.f / dden[rbase + i];
    float4 o = {acc[r][0] * inv, acc[r][1] * inv, acc[r][2] * inv, acc[r][3] * inv};
    *(float4*)(ctx + (rbase + i) * (size_t)E3n + e0 + tx * 4) = o;
  }
}

// ================= K7: predictor head ==================
__global__ __launch_bounds__(256) void k_pred(const float* __restrict__ ctx,
    const float* __restrict__ enc_w, const float* __restrict__ enc_b,
    const float* __restrict__ ln_g, const float* __restrict__ ln_b,
    const float* __restrict__ dec_w, const float* __restrict__ dec_b,
    float* __restrict__ probs) {
  __shared__ unsigned short ew[192][128];
  __shared__ unsigned short dw[128][128];
  __shared__ unsigned short cx[32][200];
  __shared__ float hb[32][133];
  __shared__ float eb[128], lg[128], lb[128], db[128];
  __shared__ float red1[32][8], red2[32][8];
  __shared__ float mu_s[32], rs_s[32];
  __shared__ float rmax[32][16], rsum[32][16];
  __shared__ float fm[32], fs[32];
  int tid = threadIdx.x;
  int r0 = blockIdx.x * 32;
  for (int idx = tid * 4; idx < 192 * 128; idx += 1024) {
    float4 v = *(const float4*)(enc_w + idx);
    int e = idx >> 7, c2 = idx & 127;
    ew[e][c2] = f2u(v.x); ew[e][c2+1] = f2u(v.y); ew[e][c2+2] = f2u(v.z); ew[e][c2+3] = f2u(v.w);
  }
  for (int idx = tid * 4; idx < 128 * 128; idx += 1024) {
    float4 v = *(const float4*)(dec_w + idx);
    int c2 = idx >> 7, t = idx & 127;
    dw[c2][t] = f2u(v.x); dw[c2][t+1] = f2u(v.y); dw[c2][t+2] = f2u(v.z); dw[c2][t+3] = f2u(v.w);
  }
  for (int idx = tid * 4; idx < 32 * 192; idx += 1024) {
    float4 v = *(const float4*)(ctx + (size_t)r0 * E3n + idx);
    int r = idx / 192, e = idx - r * 192;
    cx[r][e] = f2u(v.x); cx[r][e+1] = f2u(v.y); cx[r][e+2] = f2u(v.z); cx[r][e+3] = f2u(v.w);
  }
  if (tid < 128) { eb[tid] = enc_b[tid]; lg[tid] = ln_g[tid]; lb[tid] = ln_b[tid]; db[tid] = dec_b[tid]; }
  __syncthreads();
  int tx = tid & 15, ty = tid >> 4;
  int ra = ty * 2, rb2 = ty * 2 + 1;
  // phase 1: h = ctx @ enc_w + enc_b
  {
    float acc0[8] = {}, acc1[8] = {};
    for (int e = 0; e < 192; ++e) {
      float a0 = u2f(cx[ra][e]), a1 = u2f(cx[rb2][e]);
      uint4 wv = *(const uint4*)&ew[e][tx * 8];
      float w[8]; unpack8(wv, w);
      #pragma unroll
      for (int t = 0; t < 8; ++t) { acc0[t] += a0 * w[t]; acc1[t] += a1 * w[t]; }
    }
    #pragma unroll
    for (int t = 0; t < 8; ++t) {
      int c2 = tx * 8 + t;
      hb[ra][c2] = acc0[t] + eb[c2];
      hb[rb2][c2] = acc1[t] + eb[c2];
    }
  }
  __syncthreads();
  // phase 2: LayerNorm + exact GELU
  {
    int r = tid >> 3, sg = tid & 7;
    float s = 0.f, s2 = 0.f;
    #pragma unroll
    for (int t = 0; t < 16; ++t) { float v = hb[r][sg * 16 + t]; s += v; s2 += v * v; }
    red1[r][sg] = s; red2[r][sg] = s2;
    __syncthreads();
    if (sg == 0) {
      float S1 = 0.f, S2 = 0.f;
      #pragma unroll
      for (int t = 0; t < 8; ++t) { S1 += red1[r][t]; S2 += red2[r][t]; }
      float mu = S1 * (1.f / 128.f);
      float var = S2 * (1.f / 128.f) - mu * mu;
      mu_s[r] = mu; rs_s[r] = rsqrtf(var + LNEPS);
    }
    __syncthreads();
    float mu = mu_s[r], rs = rs_s[r];
    #pragma unroll
    for (int t = 0; t < 16; ++t) {
      int c2 = sg * 16 + t;
      float v = (hb[r][c2] - mu) * rs * lg[c2] + lb[c2];
      v = 0.5f * v * (1.f + erff(v * 0.70710678118654752f));
      hb[r][c2] = v;
    }
  }
  __syncthreads();
  // phase 3: scores + softmax
  {
    float acc0[8], acc1[8];
    #pragma unroll
    for (int t = 0; t < 8; ++t) { acc0[t] = db[tx * 8 + t]; acc1[t] = db[tx * 8 + t]; }
    for (int c2 = 0; c2 < 128; ++c2) {
      float a0 = hb[ra][c2], a1 = hb[rb2][c2];
      uint4 wv = *(const uint4*)&dw[c2][tx * 8];
      float w[8]; unpack8(wv, w);
      #pragma unroll
      for (int t = 0; t < 8; ++t) { acc0[t] += a0 * w[t]; acc1[t] += a1 * w[t]; }
    }
    float m0 = acc0[0], m1 = acc1[0];
    #pragma unroll
    for (int t = 1; t < 8; ++t) { m0 = fmaxf(m0, acc0[t]); m1 = fmaxf(m1, acc1[t]); }
    rmax[ra][tx] = m0; rmax[rb2][tx] = m1;
    __syncthreads();
    if (tid < 32) {
      float mx = rmax[tid][0];
      #pragma unroll
      for (int t = 1; t < 16; ++t) mx = fmaxf(mx, rmax[tid][t]);
      fm[tid] = mx;
    }
    __syncthreads();
    float fmx0 = fm[ra], fmx1 = fm[rb2];
    float s0 = 0.f, s1 = 0.f;
    #pragma unroll
    for (int t = 0; t < 8; ++t) {
      acc0[t] = expf(acc0[t] - fmx0); s0 += acc0[t];
      acc1[t] = expf(acc1[t] - fmx1); s1 += acc1[t];
    }
    rsum[ra][tx] = s0; rsum[rb2][tx] = s1;
    __syncthreads();
    if (tid < 32) {
      float ss = 0.f;
      #pragma unroll
      for (int t = 0; t < 16; ++t) ss += rsum[tid][t];
      fs[tid] = ss;
    }
    __syncthreads();
    float inv0 = 1.f / fs[ra], inv1 = 1.f / fs[rb2];
    float4 oa = {acc0[0]*inv0, acc0[1]*inv0, acc0[2]*inv0, acc0[3]*inv0};
    float4 ob = {acc0[4]*inv0, acc0[5]*inv0, acc0[6]*inv0, acc0[7]*inv0};
    float4 oc = {acc1[0]*inv1, acc1[1]*inv1, acc1[2]*inv1, acc1[3]*inv1};
    float4 od = {acc1[4]*inv1, acc1[5]*inv1, acc1[6]*inv1, acc1[7]*inv1};
    size_t base0 = (size_t)(r0 + ra) * Tn + tx * 8;
    size_t base1 = (size_t)(r0 + rb2) * Tn + tx * 8;
    *(float4*)(probs + base0) = oa;
    *(float4*)(probs + base0 + 4) = ob;
    *(float4*)(probs + base1) = oc;
    *(float4*)(probs + base1 + 4) = od;
  }
}

// ================= launch ==================
extern "C" void kernel_launch(void* const* d_in, const int* in_sizes, int n_in,
                              void* d_out, int out_size, void* d_ws, size_t ws_size,
                              hipStream_t stream) {
  const float* q     = (const float*)d_in[0];
  const float* k     = (const float*)d_in[1];
  const float* v3    = (const float*)d_in[2];
  const float* proj  = (const float*)d_in[3];
  const float* enc_w = (const float*)d_in[4];
  const float* enc_b = (const float*)d_in[5];
  const float* ln_g  = (const float*)d_in[6];
  const float* ln_b  = (const float*)d_in[7];
  const float* dec_w = (const float*)d_in[8];
  const float* dec_b = (const float*)d_in[9];
  float* out = (float*)d_out;
  char* ws = (char*)d_ws;
  if (ws_size < WS_NEED) return;

  unsigned short* qf   = (unsigned short*)(ws + OFF_QF);
  unsigned short* kf   = (unsigned short*)(ws + OFF_KF);
  unsigned short* qk   = (unsigned short*)(ws + OFF_QK);
  float*          dden = (float*)(ws + OFF_D);
  float*          kpre = (float*)(ws + OFF_KPRE);
  unsigned short* S    = (unsigned short*)(ws + OFF_S);
  float* ctx   = out;
  float* probs = out + (size_t)BHn * Nn * E3n;

  k_features<<<dim3(BHn * Nn / 64, 2), 256, 0, stream>>>(q, k, proj, qf, kf);
  k_ksum   <<<dim3(BHn * NCn),        256, 0, stream>>>(kf, kpre);
  k_kprefix<<<dim3(BHn),              256, 0, stream>>>(kpre);
  k_qk     <<<dim3(BHn * NCn),        256, 0, stream>>>(qf, kf, kpre, qk, dden);
  k_schunk <<<dim3(BHn * NCn, 3),     256, 0, stream>>>(kf, v3, S);
  k_sprefix<<<dim3(BHn * 51),         256, 0, stream>>>(S);
  k_ctx    <<<dim3(BHn * NCn, 3),     256, 0, stream>>>(qf, qk, S, v3, dden, ctx);
  k_pred   <<<dim3(BHn * Nn / 32),    256, 0, stream>>>(ctx, enc_w, enc_b, ln_g, ln_b,
                                                        dec_w, dec_b, probs);
}

// Round 2
// 470.191 us; speedup vs baseline: 1.1735x; 1.1735x over previous
//
#include <hip/hip_runtime.h>
#include <hip/hip_bf16.h>
#include <math.h>

// ---------------- problem constants ----------------
constexpr int Bn = 2, Hn = 12, BHn = 24;
constexpr int Nn = 2048, Dn = 64;
constexpr int Mn = 266, MPn = 272;          // M padded to 272 (zero-filled)
constexpr int E3n = 192, DHn = 128, Tn = 128;
constexpr int Cn = 128, NCn = 16;           // chunking

#define DNRM 0.35355339059327373f   // 64^-0.25
#define KEPS 1e-3f
#define DEPS 1e-6f
#define LNEPS 1e-5f

// ---------------- ws layout (bytes) ----------------
static const size_t OFF_QF   = 0;            // bf16 [BH][N][MP]   26,738,688
static const size_t OFF_KF   = 26738688;     // bf16 [BH][N][MP]
static const size_t OFF_QK   = 53477376;     // bf16 [BH][NC][C][C] 12,582,912
static const size_t OFF_D    = 66060288;     // f32  [BH][N]          196,608
static const size_t OFF_KPRE = 66256896;     // f32  [BH][NC][MP]     417,792
static const size_t OFF_S    = 66674688;     // bf16 [BH][NC][MP][E3] 40,108,032
static const size_t OFF_H    = OFF_QF;       // bf16 [BH*N][128] 12,582,912 (aliases qf; qf dead after k_ctx)
static const size_t WS_NEED  = 106782720;

// ---------------- helpers ----------------
__device__ inline float u2f(unsigned int u) {
  union { float f; unsigned int i; } c; c.i = u << 16; return c.f;
}
__device__ inline unsigned short f2u(float x) {
  __hip_bfloat16 h = __float2bfloat16(x);
  unsigned short u; __builtin_memcpy(&u, &h, 2); return u;
}
__device__ inline unsigned int pack2(float lo, float hi) {
  return (unsigned int)f2u(lo) | ((unsigned int)f2u(hi) << 16);
}
__device__ inline void unpack8(uint4 v, float* a) {
  a[0] = u2f(v.x & 0xffffu); a[1] = u2f(v.x >> 16);
  a[2] = u2f(v.y & 0xffffu); a[3] = u2f(v.y >> 16);
  a[4] = u2f(v.z & 0xffffu); a[5] = u2f(v.z >> 16);
  a[6] = u2f(v.w & 0xffffu); a[7] = u2f(v.w >> 16);
}

// ================= K1: performer features ==================
// qf/kf[row][m] = relu(dn * x[row]·proj[m]) + eps   (bf16, m>=266 -> 0)
__global__ __launch_bounds__(256) void k_features(
    const float* __restrict__ q, const float* __restrict__ k,
    const float* __restrict__ proj,
    unsigned short* __restrict__ qf, unsigned short* __restrict__ kf) {
  __shared__ float xt[64][68];   // [k][row]
  __shared__ float pt[64][68];   // [k][col]
  const float* x = (blockIdx.y == 0) ? q : k;
  unsigned short* outp = (blockIdx.y == 0) ? qf : kf;
  int tid = threadIdx.x;
  int r0 = blockIdx.x * 64;
  for (int idx = tid * 4; idx < 4096; idx += 1024) {
    int row = idx >> 6, kk = idx & 63;
    float4 v = *(const float4*)(x + (size_t)(r0 + row) * Dn + kk);
    xt[kk][row] = v.x; xt[kk+1][row] = v.y; xt[kk+2][row] = v.z; xt[kk+3][row] = v.w;
  }
  int tx = tid & 15, ty = tid >> 4;
  int rr = ty * 4, cc = tx * 4;
  for (int ct = 0; ct < 5; ++ct) {
    int c0 = ct * 64;
    __syncthreads();
    for (int idx = tid * 4; idx < 4096; idx += 1024) {
      int col = idx >> 6, kk = idx & 63;
      int p = c0 + col;
      float4 v = make_float4(0.f, 0.f, 0.f, 0.f);
      if (p < Mn) v = *(const float4*)(proj + (size_t)p * Dn + kk);
      pt[kk][col] = v.x; pt[kk+1][col] = v.y; pt[kk+2][col] = v.z; pt[kk+3][col] = v.w;
    }
    __syncthreads();
    float acc[4][4] = {};
    #pragma unroll 8
    for (int kk = 0; kk < 64; ++kk) {
      float4 av = *(const float4*)&xt[kk][rr];
      float4 bv = *(const float4*)&pt[kk][cc];
      float a[4] = {av.x, av.y, av.z, av.w};
      float b[4] = {bv.x, bv.y, bv.z, bv.w};
      #pragma unroll
      for (int i = 0; i < 4; ++i)
        #pragma unroll
        for (int j = 0; j < 4; ++j) acc[i][j] += a[i] * b[j];
    }
    int m0w = c0 + cc;
    if (m0w < MPn) {
      #pragma unroll
      for (int r = 0; r < 4; ++r) {
        int row = r0 + rr + r;
        ushort4 o;
        unsigned short* op = (unsigned short*)&o;
        #pragma unroll
        for (int s = 0; s < 4; ++s) {
          int m = m0w + s;
          float val = 0.f;
          if (m < Mn) val = fmaxf(acc[r][s] * DNRM, 0.f) + KEPS;
          op[s] = f2u(val);
        }
        *(ushort4*)(outp + (size_t)row * MPn + m0w) = o;
      }
    }
  }
}

// ================= K2a: per-chunk kf column sums ==================
__global__ __launch_bounds__(256) void k_ksum(const unsigned short* __restrict__ kf,
                                              float* __restrict__ kpre) {
  int blk = blockIdx.x; int bh = blk >> 4, c = blk & 15;
  int tid = threadIdx.x;
  for (int m = tid; m < MPn; m += 256) {
    const unsigned short* base = kf + ((size_t)bh * Nn + (size_t)c * Cn) * MPn + m;
    float s = 0.f;
    #pragma unroll 8
    for (int j = 0; j < Cn; ++j) s += u2f(base[(size_t)j * MPn]);
    kpre[((size_t)bh * NCn + c) * MPn + m] = s;
  }
}

// ================= K2b: in-place exclusive prefix over chunks ==================
__global__ __launch_bounds__(256) void k_kprefix(float* __restrict__ kpre) {
  int bh = blockIdx.x; int tid = threadIdx.x;
  for (int m = tid; m < MPn; m += 256) {
    float v[NCn];
    #pragma unroll
    for (int c = 0; c < NCn; ++c) v[c] = kpre[((size_t)bh * NCn + c) * MPn + m];
    float acc = 0.f;
    #pragma unroll
    for (int c = 0; c < NCn; ++c) {
      kpre[((size_t)bh * NCn + c) * MPn + m] = acc;
      acc += v[c];
    }
  }
}

// ================= K3: masked qk + denominator ==================
__global__ __launch_bounds__(256) void k_qk(const unsigned short* __restrict__ qf,
                                            const unsigned short* __restrict__ kf,
                                            const float* __restrict__ kpre,
                                            unsigned short* __restrict__ qk,
                                            float* __restrict__ dden) {
  __shared__ unsigned short qt[16][128];   // [m-local][i]
  __shared__ unsigned short kt[16][128];   // [m-local][j]
  __shared__ float kp[MPn];
  __shared__ float red[128][17];
  int blk = blockIdx.x;
  int bh = blk >> 4, c = blk & 15;
  int tid = threadIdx.x;
  int tx = tid & 15, ty = tid >> 4;
  int li = tid & 127, mg = tid >> 7;
  size_t qbase = ((size_t)bh * Nn + (size_t)c * Cn) * MPn;
  for (int m = tid; m < MPn; m += 256) kp[m] = kpre[((size_t)bh * NCn + c) * MPn + m];
  float acc[8][8] = {};
  for (int mt = 0; mt < MPn; mt += 16) {
    __syncthreads();
    {
      uint4 v = *(const uint4*)(qf + qbase + (size_t)li * MPn + mt + mg * 8);
      unsigned short tmp[8]; __builtin_memcpy(tmp, &v, 16);
      #pragma unroll
      for (int t = 0; t < 8; ++t) qt[mg * 8 + t][li] = tmp[t];
      uint4 w = *(const uint4*)(kf + qbase + (size_t)li * MPn + mt + mg * 8);
      __builtin_memcpy(tmp, &w, 16);
      #pragma unroll
      for (int t = 0; t < 8; ++t) kt[mg * 8 + t][li] = tmp[t];
    }
    __syncthreads();
    #pragma unroll 4
    for (int mm = 0; mm < 16; ++mm) {
      uint4 av = *(const uint4*)&qt[mm][ty * 8];
      uint4 bv = *(const uint4*)&kt[mm][tx * 8];
      float a[8], b[8];
      unpack8(av, a); unpack8(bv, b);
      #pragma unroll
      for (int r = 0; r < 8; ++r)
        #pragma unroll
        for (int s = 0; s < 8; ++s) acc[r][s] += a[r] * b[s];
    }
  }
  int i0 = ty * 8, j0 = tx * 8;
  #pragma unroll
  for (int r = 0; r < 8; ++r) {
    float s = 0.f;
    #pragma unroll
    for (int t = 0; t < 8; ++t) {
      if (j0 + t > i0 + r) acc[r][t] = 0.f;
      s += acc[r][t];
    }
    red[i0 + r][tx] = s;
  }
  __syncthreads();
  if (tid < 128) {
    float s = 0.f;
    #pragma unroll
    for (int t = 0; t < 16; ++t) s += red[tid][t];
    float dot = 0.f, qs = 0.f;
    const unsigned short* qrow = qf + qbase + (size_t)tid * MPn;
    for (int m = 0; m < MPn; m += 8) {
      uint4 v = *(const uint4*)(qrow + m);
      float a[8]; unpack8(v, a);
      #pragma unroll
      for (int t = 0; t < 8; ++t) { dot += a[t] * kp[m + t]; qs += a[t]; }
    }
    dden[(size_t)bh * Nn + (size_t)c * Cn + tid] = s + dot + DEPS * qs;
  }
  size_t qkbase = (size_t)blk * (Cn * Cn);
  #pragma unroll
  for (int r = 0; r < 8; ++r) {
    ushort4 o0, o1;
    unsigned short* p0 = (unsigned short*)&o0;
    unsigned short* p1 = (unsigned short*)&o1;
    #pragma unroll
    for (int t = 0; t < 4; ++t) { p0[t] = f2u(acc[r][t]); p1[t] = f2u(acc[r][t + 4]); }
    unsigned short* dst = qk + qkbase + (size_t)(i0 + r) * Cn + j0;
    *(ushort4*)dst = o0;
    *(ushort4*)(dst + 4) = o1;
  }
}

// ================= K4: per-chunk S_c = kf_c^T @ v_c ==================
__global__ __launch_bounds__(256) void k_schunk(const unsigned short* __restrict__ kf,
                                                const float* __restrict__ v3,
                                                unsigned short* __restrict__ S) {
  __shared__ float vt[128][64];            // [j][e-local]
  __shared__ unsigned short kft[128][64];  // [j][m-local]
  int blk = blockIdx.x, ey = blockIdx.y;
  int bh = blk >> 4, c = blk & 15;
  int e0 = ey * 64;
  int tid = threadIdx.x, tx = tid & 15, ty = tid >> 4;
  size_t vbase = ((size_t)bh * Nn + (size_t)c * Cn) * E3n + e0;
  for (int idx = tid * 4; idx < 8192; idx += 1024) {
    int j = idx >> 6, e = idx & 63;
    *(float4*)&vt[j][e] = *(const float4*)(v3 + vbase + (size_t)j * E3n + e);
  }
  size_t kbase = ((size_t)bh * Nn + (size_t)c * Cn) * MPn;
  size_t Sbase = (size_t)blk * MPn * E3n;
  for (int mb = 0; mb < 5; ++mb) {
    int m0 = mb * 64;
    __syncthreads();
    for (int idx = tid * 8; idx < 8192; idx += 2048) {
      int j = idx >> 6, ml = idx & 63;
      int m = m0 + ml;
      uint4 v = make_uint4(0u, 0u, 0u, 0u);
      if (m < MPn) v = *(const uint4*)(kf + kbase + (size_t)j * MPn + m);
      *(uint4*)&kft[j][ml] = v;
    }
    __syncthreads();
    float acc[4][4] = {};
    for (int j = 0; j < 128; ++j) {
      ushort4 kv = *(const ushort4*)&kft[j][ty * 4];
      float4 bv = *(const float4*)&vt[j][tx * 4];
      float a[4] = {u2f(kv.x), u2f(kv.y), u2f(kv.z), u2f(kv.w)};
      float b[4] = {bv.x, bv.y, bv.z, bv.w};
      #pragma unroll
      for (int r = 0; r < 4; ++r)
        #pragma unroll
        for (int s = 0; s < 4; ++s) acc[r][s] += a[r] * b[s];
    }
    #pragma unroll
    for (int r = 0; r < 4; ++r) {
      int m = m0 + ty * 4 + r;
      if (m < MPn) {
        ushort4 o;
        unsigned short* op = (unsigned short*)&o;
        #pragma unroll
        for (int s = 0; s < 4; ++s) op[s] = f2u(acc[r][s]);
        *(ushort4*)(S + Sbase + (size_t)m * E3n + e0 + tx * 4) = o;
      }
    }
  }
}

// ================= K5: in-place exclusive prefix of S over chunks ==================
__global__ __launch_bounds__(256) void k_sprefix(unsigned short* __restrict__ S) {
  int bh = blockIdx.x / 51, sub = blockIdx.x % 51;
  int idx4 = sub * 256 + threadIdx.x;          // 51*256 == MPn*E3n/4 exactly
  size_t off = (size_t)idx4 * 4;
  ushort4 v[NCn];
  #pragma unroll
  for (int c = 0; c < NCn; ++c)
    v[c] = *(const ushort4*)(S + ((size_t)(bh * NCn + c)) * MPn * E3n + off);
  float a0 = 0.f, a1 = 0.f, a2 = 0.f, a3 = 0.f;
  #pragma unroll
  for (int c = 0; c < NCn; ++c) {
    ushort4 o;
    unsigned short* op = (unsigned short*)&o;
    op[0] = f2u(a0); op[1] = f2u(a1); op[2] = f2u(a2); op[3] = f2u(a3);
    *(ushort4*)(S + ((size_t)(bh * NCn + c)) * MPn * E3n + off) = o;
    a0 += u2f(v[c].x); a1 += u2f(v[c].y); a2 += u2f(v[c].z); a3 += u2f(v[c].w);
  }
}

// ================= K6: ctx = (qf@S_pre + qk@v) / d ==================
__global__ __launch_bounds__(256) void k_ctx(const unsigned short* __restrict__ qf,
                                             const unsigned short* __restrict__ qk,
                                             const unsigned short* __restrict__ S,
                                             const float* __restrict__ v3,
                                             const float* __restrict__ dden,
                                             float* __restrict__ ctx) {
  __shared__ unsigned short qt[16][128];
  __shared__ unsigned short st[16][64];
  __shared__ unsigned short qkt[16][128];
  __shared__ float vt[16][64];
  int blk = blockIdx.x, ey = blockIdx.y;
  int bh = blk >> 4, c = blk & 15;
  int e0 = ey * 64;
  int tid = threadIdx.x, tx = tid & 15, ty = tid >> 4;
  int li = tid & 127, g = tid >> 7;
  size_t qbase = ((size_t)bh * Nn + (size_t)c * Cn) * MPn;
  size_t Sbase = (size_t)blk * MPn * E3n;
  float acc[8][4] = {};
  for (int mt = 0; mt < MPn; mt += 16) {
    __syncthreads();
    {
      uint4 v = *(const uint4*)(qf + qbase + (size_t)li * MPn + mt + g * 8);
      unsigned short tmp[8]; __builtin_memcpy(tmp, &v, 16);
      #pragma unroll
      for (int t = 0; t < 8; ++t) qt[g * 8 + t][li] = tmp[t];
    }
    {
      int idx = tid * 4;
      int mm = idx >> 6, el = idx & 63;
      ushort4 v = *(const ushort4*)(S + Sbase + (size_t)(mt + mm) * E3n + e0 + el);
      *(ushort4*)&st[mm][el] = v;
    }
    __syncthreads();
    #pragma unroll 4
    for (int mm = 0; mm < 16; ++mm) {
      uint4 av = *(const uint4*)&qt[mm][ty * 8];
      float a[8]; unpack8(av, a);
      ushort4 bv = *(const ushort4*)&st[mm][tx * 4];
      float b[4] = {u2f(bv.x), u2f(bv.y), u2f(bv.z), u2f(bv.w)};
      #pragma unroll
      for (int r = 0; r < 8; ++r)
        #pragma unroll
        for (int s = 0; s < 4; ++s) acc[r][s] += a[r] * b[s];
    }
  }
  size_t qkbase = (size_t)blk * (Cn * Cn);
  size_t vbase = ((size_t)bh * Nn + (size_t)c * Cn) * E3n + e0;
  for (int jt = 0; jt < Cn; jt += 16) {
    __syncthreads();
    {
      uint4 v = *(const uint4*)(qk + qkbase + (size_t)li * Cn + jt + g * 8);
      unsigned short tmp[8]; __builtin_memcpy(tmp, &v, 16);
      #pragma unroll
      for (int t = 0; t < 8; ++t) qkt[g * 8 + t][li] = tmp[t];
    }
    {
      int idx = tid * 4;
      int jj = idx >> 6, el = idx & 63;
      *(float4*)&vt[jj][el] = *(const float4*)(v3 + vbase + (size_t)(jt + jj) * E3n + el);
    }
    __syncthreads();
    #pragma unroll 4
    for (int jj = 0; jj < 16; ++jj) {
      uint4 av = *(const uint4*)&qkt[jj][ty * 8];
      float a[8]; unpack8(av, a);
      float4 bv = *(const float4*)&vt[jj][tx * 4];
      float b[4] = {bv.x, bv.y, bv.z, bv.w};
      #pragma unroll
      for (int r = 0; r < 8; ++r)
        #pragma unroll
        for (int s = 0; s < 4; ++s) acc[r][s] += a[r] * b[s];
    }
  }
  size_t rbase = (size_t)bh * Nn + (size_t)c * Cn;
  #pragma unroll
  for (int r = 0; r < 8; ++r) {
    int i = ty * 8 + r;
    float inv = 1.f / dden[rbase + i];
    float4 o = {acc[r][0] * inv, acc[r][1] * inv, acc[r][2] * inv, acc[r][3] * inv};
    *(float4*)(ctx + (rbase + i) * (size_t)E3n + e0 + tx * 4) = o;
  }
}

// ================= K7a: h = GELU(LN(ctx @ enc_w + enc_b)) -> bf16 ==================
// 64 rows/block; enc_w streamed from global (L2-resident); LN via shfl over tx group.
__global__ __launch_bounds__(256) void k_enc(const float* __restrict__ ctx,
    const float* __restrict__ enc_w, const float* __restrict__ enc_b,
    const float* __restrict__ ln_g, const float* __restrict__ ln_b,
    unsigned short* __restrict__ h) {
  __shared__ float ct[64][200];   // pad 200: a-reads hit 4 distinct banks
  int tid = threadIdx.x;
  int r0 = blockIdx.x * 64;
  #pragma unroll
  for (int it = 0; it < 12; ++it) {
    int idx = tid * 4 + it * 1024;
    int row = idx / 192, e = idx % 192;
    float4 v = *(const float4*)(ctx + (size_t)(r0 + row) * E3n + e);
    *(float4*)&ct[row][e] = v;
  }
  __syncthreads();
  int tx = tid & 15, ty = tid >> 4;
  float acc[4][8] = {};
  #pragma unroll 2
  for (int e = 0; e < E3n; ++e) {
    float4 w0 = *(const float4*)(enc_w + (size_t)e * DHn + tx * 8);
    float4 w1 = *(const float4*)(enc_w + (size_t)e * DHn + tx * 8 + 4);
    float w[8] = {w0.x, w0.y, w0.z, w0.w, w1.x, w1.y, w1.z, w1.w};
    #pragma unroll
    for (int i = 0; i < 4; ++i) {
      float a = ct[ty + 16 * i][e];
      #pragma unroll
      for (int j = 0; j < 8; ++j) acc[i][j] += a * w[j];
    }
  }
  float4 b0 = *(const float4*)(enc_b + tx * 8);
  float4 b1 = *(const float4*)(enc_b + tx * 8 + 4);
  float bb[8] = {b0.x, b0.y, b0.z, b0.w, b1.x, b1.y, b1.z, b1.w};
  float4 g0 = *(const float4*)(ln_g + tx * 8);
  float4 g1 = *(const float4*)(ln_g + tx * 8 + 4);
  float gg[8] = {g0.x, g0.y, g0.z, g0.w, g1.x, g1.y, g1.z, g1.w};
  float4 l0 = *(const float4*)(ln_b + tx * 8);
  float4 l1 = *(const float4*)(ln_b + tx * 8 + 4);
  float ll[8] = {l0.x, l0.y, l0.z, l0.w, l1.x, l1.y, l1.z, l1.w};
  #pragma unroll
  for (int i = 0; i < 4; ++i) {
    float s = 0.f, s2 = 0.f;
    #pragma unroll
    for (int j = 0; j < 8; ++j) {
      acc[i][j] += bb[j];
      s += acc[i][j]; s2 += acc[i][j] * acc[i][j];
    }
    #pragma unroll
    for (int m = 1; m < 16; m <<= 1) {
      s += __shfl_xor(s, m);
      s2 += __shfl_xor(s2, m);
    }
    float mu = s * (1.f / 128.f);
    float var = s2 * (1.f / 128.f) - mu * mu;
    float rs = rsqrtf(var + LNEPS);
    uint4 o;
    unsigned int* op = (unsigned int*)&o;
    #pragma unroll
    for (int j2 = 0; j2 < 4; ++j2) {
      float v0 = (acc[i][2 * j2] - mu) * rs * gg[2 * j2] + ll[2 * j2];
      float v1 = (acc[i][2 * j2 + 1] - mu) * rs * gg[2 * j2 + 1] + ll[2 * j2 + 1];
      v0 = 0.5f * v0 * (1.f + erff(v0 * 0.70710678118654752f));
      v1 = 0.5f * v1 * (1.f + erff(v1 * 0.70710678118654752f));
      op[j2] = pack2(v0, v1);
    }
    *(uint4*)(h + (size_t)(r0 + ty + 16 * i) * DHn + tx * 8) = o;
  }
}

// ================= K7b: probs = softmax(h @ dec_w + dec_b) ==================
__global__ __launch_bounds__(256) void k_dec(const unsigned short* __restrict__ h,
    const float* __restrict__ dec_w, const float* __restrict__ dec_b,
    float* __restrict__ probs) {
  __shared__ float ht[64][136];   // pad 136: a-reads hit 4 distinct banks
  int tid = threadIdx.x;
  int r0 = blockIdx.x * 64;
  #pragma unroll
  for (int it = 0; it < 4; ++it) {
    int idx = tid * 8 + it * 2048;
    int row = idx >> 7, c = idx & 127;
    uint4 u = *(const uint4*)(h + (size_t)(r0 + row) * DHn + c);
    float a[8]; unpack8(u, a);
    *(float4*)&ht[row][c] = make_float4(a[0], a[1], a[2], a[3]);
    *(float4*)&ht[row][c + 4] = make_float4(a[4], a[5], a[6], a[7]);
  }
  __syncthreads();
  int tx = tid & 15, ty = tid >> 4;
  float acc[4][8] = {};
  #pragma unroll 2
  for (int c = 0; c < DHn; ++c) {
    float4 w0 = *(const float4*)(dec_w + (size_t)c * Tn + tx * 8);
    float4 w1 = *(const float4*)(dec_w + (size_t)c * Tn + tx * 8 + 4);
    float w[8] = {w0.x, w0.y, w0.z, w0.w, w1.x, w1.y, w1.z, w1.w};
    #pragma unroll
    for (int i = 0; i < 4; ++i) {
      float a = ht[ty + 16 * i][c];
      #pragma unroll
      for (int j = 0; j < 8; ++j) acc[i][j] += a * w[j];
    }
  }
  float4 b0 = *(const float4*)(dec_b + tx * 8);
  float4 b1 = *(const float4*)(dec_b + tx * 8 + 4);
  float bb[8] = {b0.x, b0.y, b0.z, b0.w, b1.x, b1.y, b1.z, b1.w};
  #pragma unroll
  for (int i = 0; i < 4; ++i) {
    float m = -1e30f;
    #pragma unroll
    for (int j = 0; j < 8; ++j) {
      acc[i][j] += bb[j];
      m = fmaxf(m, acc[i][j]);
    }
    #pragma unroll
    for (int mm = 1; mm < 16; mm <<= 1) m = fmaxf(m, __shfl_xor(m, mm));
    float s = 0.f;
    #pragma unroll
    for (int j = 0; j < 8; ++j) { acc[i][j] = expf(acc[i][j] - m); s += acc[i][j]; }
    #pragma unroll
    for (int mm = 1; mm < 16; mm <<= 1) s += __shfl_xor(s, mm);
    float inv = 1.f / s;
    float4 oa = {acc[i][0] * inv, acc[i][1] * inv, acc[i][2] * inv, acc[i][3] * inv};
    float4 ob = {acc[i][4] * inv, acc[i][5] * inv, acc[i][6] * inv, acc[i][7] * inv};
    size_t base = (size_t)(r0 + ty + 16 * i) * Tn + tx * 8;
    *(float4*)(probs + base) = oa;
    *(float4*)(probs + base + 4) = ob;
  }
}

// ================= launch ==================
extern "C" void kernel_launch(void* const* d_in, const int* in_sizes, int n_in,
                              void* d_out, int out_size, void* d_ws, size_t ws_size,
                              hipStream_t stream) {
  const float* q     = (const float*)d_in[0];
  const float* k     = (const float*)d_in[1];
  const float* v3    = (const float*)d_in[2];
  const float* proj  = (const float*)d_in[3];
  const float* enc_w = (const float*)d_in[4];
  const float* enc_b = (const float*)d_in[5];
  const float* ln_g  = (const float*)d_in[6];
  const float* ln_b  = (const float*)d_in[7];
  const float* dec_w = (const float*)d_in[8];
  const float* dec_b = (const float*)d_in[9];
  float* out = (float*)d_out;
  char* ws = (char*)d_ws;
  if (ws_size < WS_NEED) return;

  unsigned short* qf   = (unsigned short*)(ws + OFF_QF);
  unsigned short* kf   = (unsigned short*)(ws + OFF_KF);
  unsigned short* qk   = (unsigned short*)(ws + OFF_QK);
  float*          dden = (float*)(ws + OFF_D);
  float*          kpre = (float*)(ws + OFF_KPRE);
  unsigned short* S    = (unsigned short*)(ws + OFF_S);
  unsigned short* hbuf = (unsigned short*)(ws + OFF_H);   // aliases qf (dead after k_ctx)
  float* ctx   = out;
  float* probs = out + (size_t)BHn * Nn * E3n;

  k_features<<<dim3(BHn * Nn / 64, 2), 256, 0, stream>>>(q, k, proj, qf, kf);
  k_ksum   <<<dim3(BHn * NCn),        256, 0, stream>>>(kf, kpre);
  k_kprefix<<<dim3(BHn),              256, 0, stream>>>(kpre);
  k_qk     <<<dim3(BHn * NCn),        256, 0, stream>>>(qf, kf, kpre, qk, dden);
  k_schunk <<<dim3(BHn * NCn, 3),     256, 0, stream>>>(kf, v3, S);
  k_sprefix<<<dim3(BHn * 51),         256, 0, stream>>>(S);
  k_ctx    <<<dim3(BHn * NCn, 3),     256, 0, stream>>>(qf, qk, S, v3, dden, ctx);
  k_enc    <<<dim3(BHn * Nn / 64),    256, 0, stream>>>(ctx, enc_w, enc_b, ln_g, ln_b, hbuf);
  k_dec    <<<dim3(BHn * Nn / 64),    256, 0, stream>>>(hbuf, dec_w, dec_b, probs);
}

// Round 3
// 333.773 us; speedup vs baseline: 1.6531x; 1.4087x over previous
//
#include <hip/hip_runtime.h>
#include <hip/hip_bf16.h>
#include <math.h>

// ---------------- problem constants ----------------
constexpr int Bn = 2, Hn = 12, BHn = 24;
constexpr int Nn = 2048, Dn = 64;
constexpr int Mn = 266, MPn = 272;          // M padded to 272 (zero-filled)
constexpr int E3n = 192, DHn = 128, Tn = 128;
constexpr int Cn = 128, NCn = 16;           // chunking

#define DNRM 0.35355339059327373f   // 64^-0.25
#define KEPS 1e-3f
#define DEPS 1e-6f
#define LNEPS 1e-5f

// ---------------- ws layout (bytes) ----------------
static const size_t OFF_QF   = 0;            // bf16 [BH][N][MP]   26,738,688
static const size_t OFF_KF   = 26738688;     // bf16 [BH][N][MP]
static const size_t OFF_QK   = 53477376;     // bf16 [BH][NC][C][C] 12,582,912
static const size_t OFF_D    = 66060288;     // f32  [BH][N]          196,608
static const size_t OFF_KPRE = 66256896;     // f32  [BH][NC][MP]     417,792
static const size_t OFF_S    = 66674688;     // bf16 [BH][NC][192][272] (S^T) 40,108,032
static const size_t OFF_H    = OFF_QF;       // bf16 [BH*N][128] (aliases qf; dead after k_ctx)
static const size_t OFF_VT   = OFF_KF;       // bf16 [BH][192][2048] 18,874,368 (aliases kf; dead after k_schunk)
static const size_t WS_NEED  = 106782720;

// ---------------- helpers ----------------
using bf16x8 = __attribute__((ext_vector_type(8))) short;
using f32x4  = __attribute__((ext_vector_type(4))) float;

__device__ inline float u2f(unsigned int u) {
  union { float f; unsigned int i; } c; c.i = u << 16; return c.f;
}
__device__ inline unsigned short f2u(float x) {
  __hip_bfloat16 h = __float2bfloat16(x);
  unsigned short u; __builtin_memcpy(&u, &h, 2); return u;
}
__device__ inline unsigned int pack2(float lo, float hi) {
  return (unsigned int)f2u(lo) | ((unsigned int)f2u(hi) << 16);
}
__device__ inline void unpack8(uint4 v, float* a) {
  a[0] = u2f(v.x & 0xffffu); a[1] = u2f(v.x >> 16);
  a[2] = u2f(v.y & 0xffffu); a[3] = u2f(v.y >> 16);
  a[4] = u2f(v.z & 0xffffu); a[5] = u2f(v.z >> 16);
  a[6] = u2f(v.w & 0xffffu); a[7] = u2f(v.w >> 16);
}

// ================= K1: performer features ==================
__global__ __launch_bounds__(256) void k_features(
    const float* __restrict__ q, const float* __restrict__ k,
    const float* __restrict__ proj,
    unsigned short* __restrict__ qf, unsigned short* __restrict__ kf) {
  __shared__ float xt[64][68];   // [k][row]
  __shared__ float pt[64][68];   // [k][col]
  const float* x = (blockIdx.y == 0) ? q : k;
  unsigned short* outp = (blockIdx.y == 0) ? qf : kf;
  int tid = threadIdx.x;
  int r0 = blockIdx.x * 64;
  for (int idx = tid * 4; idx < 4096; idx += 1024) {
    int row = idx >> 6, kk = idx & 63;
    float4 v = *(const float4*)(x + (size_t)(r0 + row) * Dn + kk);
    xt[kk][row] = v.x; xt[kk+1][row] = v.y; xt[kk+2][row] = v.z; xt[kk+3][row] = v.w;
  }
  int tx = tid & 15, ty = tid >> 4;
  int rr = ty * 4, cc = tx * 4;
  for (int ct = 0; ct < 5; ++ct) {
    int c0 = ct * 64;
    __syncthreads();
    for (int idx = tid * 4; idx < 4096; idx += 1024) {
      int col = idx >> 6, kk = idx & 63;
      int p = c0 + col;
      float4 v = make_float4(0.f, 0.f, 0.f, 0.f);
      if (p < Mn) v = *(const float4*)(proj + (size_t)p * Dn + kk);
      pt[kk][col] = v.x; pt[kk+1][col] = v.y; pt[kk+2][col] = v.z; pt[kk+3][col] = v.w;
    }
    __syncthreads();
    float acc[4][4] = {};
    #pragma unroll 8
    for (int kk = 0; kk < 64; ++kk) {
      float4 av = *(const float4*)&xt[kk][rr];
      float4 bv = *(const float4*)&pt[kk][cc];
      float a[4] = {av.x, av.y, av.z, av.w};
      float b[4] = {bv.x, bv.y, bv.z, bv.w};
      #pragma unroll
      for (int i = 0; i < 4; ++i)
        #pragma unroll
        for (int j = 0; j < 4; ++j) acc[i][j] += a[i] * b[j];
    }
    int m0w = c0 + cc;
    if (m0w < MPn) {
      #pragma unroll
      for (int r = 0; r < 4; ++r) {
        int row = r0 + rr + r;
        ushort4 o;
        unsigned short* op = (unsigned short*)&o;
        #pragma unroll
        for (int s = 0; s < 4; ++s) {
          int m = m0w + s;
          float val = 0.f;
          if (m < Mn) val = fmaxf(acc[r][s] * DNRM, 0.f) + KEPS;
          op[s] = f2u(val);
        }
        *(ushort4*)(outp + (size_t)row * MPn + m0w) = o;
      }
    }
  }
}

// ================= K2a: per-chunk kf column sums ==================
__global__ __launch_bounds__(256) void k_ksum(const unsigned short* __restrict__ kf,
                                              float* __restrict__ kpre) {
  int blk = blockIdx.x; int bh = blk >> 4, c = blk & 15;
  int tid = threadIdx.x;
  for (int m = tid; m < MPn; m += 256) {
    const unsigned short* base = kf + ((size_t)bh * Nn + (size_t)c * Cn) * MPn + m;
    float s = 0.f;
    #pragma unroll 8
    for (int j = 0; j < Cn; ++j) s += u2f(base[(size_t)j * MPn]);
    kpre[((size_t)bh * NCn + c) * MPn + m] = s;
  }
}

// ================= K2b: in-place exclusive prefix over chunks ==================
__global__ __launch_bounds__(256) void k_kprefix(float* __restrict__ kpre) {
  int bh = blockIdx.x; int tid = threadIdx.x;
  for (int m = tid; m < MPn; m += 256) {
    float v[NCn];
    #pragma unroll
    for (int c = 0; c < NCn; ++c) v[c] = kpre[((size_t)bh * NCn + c) * MPn + m];
    float acc = 0.f;
    #pragma unroll
    for (int c = 0; c < NCn; ++c) {
      kpre[((size_t)bh * NCn + c) * MPn + m] = acc;
      acc += v[c];
    }
  }
}

// ================= K3: MFMA masked qk + denominator ==================
// D[128x128] = qf_c @ kf_c^T (both row-major over K=m -> natural MFMA B^T form)
__global__ __launch_bounds__(256) void k_qk_mfma(
    const unsigned short* __restrict__ qf,
    const unsigned short* __restrict__ kf,
    const float* __restrict__ kpre,
    unsigned short* __restrict__ qkout,
    float* __restrict__ dden) {
  __shared__ unsigned short at[128][40];   // qf tile, pad-40 (bank step 20 -> conflict-free)
  __shared__ unsigned short ktl[128][40];  // kf tile
  __shared__ float kp[MPn];
  __shared__ float rs_lds[128];
  int blk = blockIdx.x;
  int bh = blk >> 4, c = blk & 15;
  int tid = threadIdx.x;
  int w = tid >> 6, l = tid & 63;
  int l16 = l & 15, lg = l >> 4;
  size_t qbase = ((size_t)bh * Nn + (size_t)c * Cn) * MPn;
  size_t rbase = (size_t)bh * Nn + (size_t)c * Cn;
  for (int m = tid; m < MPn; m += 256) kp[m] = kpre[((size_t)bh * NCn + c) * MPn + m];

  f32x4 acc[2][8] = {};
  for (int kt = 0; kt < 9; ++kt) {
    int mt = kt * 32;
    __syncthreads();
    #pragma unroll
    for (int p = 0; p < 2; ++p) {
      int idx = tid * 8 + p * 2048;
      int r = idx >> 5, kk = idx & 31;
      uint4 va = make_uint4(0u,0u,0u,0u), vk = make_uint4(0u,0u,0u,0u);
      if (mt + kk < MPn) {
        va = *(const uint4*)(qf + qbase + (size_t)r * MPn + mt + kk);
        vk = *(const uint4*)(kf + qbase + (size_t)r * MPn + mt + kk);
      }
      *(uint4*)((char*)&at[0][0] + r * 80 + kk * 2) = va;
      *(uint4*)((char*)&ktl[0][0] + r * 80 + kk * 2) = vk;
    }
    __syncthreads();
    bf16x8 a0 = *(const bf16x8*)((const char*)&at[0][0] + (w*32 + l16) * 80 + lg * 16);
    bf16x8 a1 = *(const bf16x8*)((const char*)&at[0][0] + (w*32 + 16 + l16) * 80 + lg * 16);
    #pragma unroll
    for (int ct = 0; ct < 8; ++ct) {
      bf16x8 b = *(const bf16x8*)((const char*)&ktl[0][0] + (ct*16 + l16) * 80 + lg * 16);
      acc[0][ct] = __builtin_amdgcn_mfma_f32_16x16x32_bf16(a0, b, acc[0][ct], 0, 0, 0);
      acc[1][ct] = __builtin_amdgcn_mfma_f32_16x16x32_bf16(a1, b, acc[1][ct], 0, 0, 0);
    }
  }
  // epilogue: mask (col<=row), write bf16, accumulate row sums
  size_t qkbase = (size_t)blk * (Cn * Cn);
  float rs[2][4] = {};
  #pragma unroll
  for (int rt = 0; rt < 2; ++rt)
    #pragma unroll
    for (int ct = 0; ct < 8; ++ct)
      #pragma unroll
      for (int reg = 0; reg < 4; ++reg) {
        int row = w*32 + rt*16 + lg*4 + reg;
        int col = ct*16 + l16;
        float v = (col <= row) ? acc[rt][ct][reg] : 0.f;
        qkout[qkbase + (size_t)row * Cn + col] = f2u(v);
        rs[rt][reg] += v;
      }
  #pragma unroll
  for (int rt = 0; rt < 2; ++rt)
    #pragma unroll
    for (int reg = 0; reg < 4; ++reg) {
      float s = rs[rt][reg];
      s += __shfl_xor(s, 1); s += __shfl_xor(s, 2);
      s += __shfl_xor(s, 4); s += __shfl_xor(s, 8);
      rs[rt][reg] = s;
    }
  if (l16 == 0) {
    #pragma unroll
    for (int rt = 0; rt < 2; ++rt)
      #pragma unroll
      for (int reg = 0; reg < 4; ++reg)
        rs_lds[w*32 + rt*16 + lg*4 + reg] = rs[rt][reg];
  }
  __syncthreads();
  if (tid < 128) {
    float dot = 0.f, qs = 0.f;
    const unsigned short* qrow = qf + qbase + (size_t)tid * MPn;
    for (int m = 0; m < MPn; m += 8) {
      uint4 v = *(const uint4*)(qrow + m);
      float a[8]; unpack8(v, a);
      #pragma unroll
      for (int t = 0; t < 8; ++t) { dot += a[t] * kp[m + t]; qs += a[t]; }
    }
    dden[rbase + tid] = rs_lds[tid] + dot + DEPS * qs;
  }
}

// ================= K4: per-chunk S^T_c = (kf_c^T @ v_c)^T -> [e][m] ==================
__global__ __launch_bounds__(256) void k_schunk(const unsigned short* __restrict__ kf,
                                                const float* __restrict__ v3,
                                                unsigned short* __restrict__ ST) {
  __shared__ float vt[128][64];            // [j][e-local]
  __shared__ unsigned short kft[128][64];  // [j][m-local]
  int blk = blockIdx.x, ey = blockIdx.y;
  int bh = blk >> 4, c = blk & 15;
  int e0 = ey * 64;
  int tid = threadIdx.x, tx = tid & 15, ty = tid >> 4;
  size_t vbase = ((size_t)bh * Nn + (size_t)c * Cn) * E3n + e0;
  for (int idx = tid * 4; idx < 8192; idx += 1024) {
    int j = idx >> 6, e = idx & 63;
    *(float4*)&vt[j][e] = *(const float4*)(v3 + vbase + (size_t)j * E3n + e);
  }
  size_t kbase = ((size_t)bh * Nn + (size_t)c * Cn) * MPn;
  size_t Sbase = (size_t)blk * MPn * E3n;    // S^T [192][272]
  for (int mb = 0; mb < 5; ++mb) {
    int m0 = mb * 64;
    __syncthreads();
    for (int idx = tid * 8; idx < 8192; idx += 2048) {
      int j = idx >> 6, ml = idx & 63;
      int m = m0 + ml;
      uint4 v = make_uint4(0u, 0u, 0u, 0u);
      if (m < MPn) v = *(const uint4*)(kf + kbase + (size_t)j * MPn + m);
      *(uint4*)&kft[j][ml] = v;
    }
    __syncthreads();
    float acc[4][4] = {};   // [e-local r][m-local s]
    for (int j = 0; j < 128; ++j) {
      ushort4 kv = *(const ushort4*)&kft[j][tx * 4];   // m values (tx)
      float4 bv = *(const float4*)&vt[j][ty * 4];      // e values (ty)
      float a[4] = {u2f(kv.x), u2f(kv.y), u2f(kv.z), u2f(kv.w)};
      float b[4] = {bv.x, bv.y, bv.z, bv.w};
      #pragma unroll
      for (int r = 0; r < 4; ++r)
        #pragma unroll
        for (int s = 0; s < 4; ++s) acc[r][s] += b[r] * a[s];
    }
    int m = m0 + tx * 4;
    if (m < MPn) {
      #pragma unroll
      for (int r = 0; r < 4; ++r) {
        int e = e0 + ty * 4 + r;
        ushort4 o;
        unsigned short* op = (unsigned short*)&o;
        #pragma unroll
        for (int s = 0; s < 4; ++s) op[s] = f2u(acc[r][s]);
        *(ushort4*)(ST + Sbase + (size_t)e * MPn + m) = o;
      }
    }
  }
}

// ================= K5: in-place exclusive prefix of S^T over chunks (flat) ==========
__global__ __launch_bounds__(256) void k_sprefix(unsigned short* __restrict__ S) {
  int bh = blockIdx.x / 51, sub = blockIdx.x % 51;
  int idx4 = sub * 256 + threadIdx.x;          // 51*256 == MPn*E3n/4 exactly
  size_t off = (size_t)idx4 * 4;
  ushort4 v[NCn];
  #pragma unroll
  for (int c = 0; c < NCn; ++c)
    v[c] = *(const ushort4*)(S + ((size_t)(bh * NCn + c)) * MPn * E3n + off);
  float a0 = 0.f, a1 = 0.f, a2 = 0.f, a3 = 0.f;
  #pragma unroll
  for (int c = 0; c < NCn; ++c) {
    ushort4 o;
    unsigned short* op = (unsigned short*)&o;
    op[0] = f2u(a0); op[1] = f2u(a1); op[2] = f2u(a2); op[3] = f2u(a3);
    *(ushort4*)(S + ((size_t)(bh * NCn + c)) * MPn * E3n + off) = o;
    a0 += u2f(v[c].x); a1 += u2f(v[c].y); a2 += u2f(v[c].z); a3 += u2f(v[c].w);
  }
}

// ================= K5b: vT[bh][e][n] = bf16(v3[bh][n][e]) ==================
__global__ __launch_bounds__(256) void k_vt(const float* __restrict__ v3,
                                            unsigned short* __restrict__ vT) {
  __shared__ unsigned short tl[64][200];
  int bh = blockIdx.x >> 5, n0 = (blockIdx.x & 31) * 64;
  int tid = threadIdx.x;
  #pragma unroll
  for (int it = 0; it < 12; ++it) {
    int idx = tid * 4 + it * 1024;
    int r = idx / 192, e = idx % 192;
    float4 v = *(const float4*)(v3 + ((size_t)bh * Nn + n0 + r) * E3n + e);
    tl[r][e] = f2u(v.x); tl[r][e+1] = f2u(v.y); tl[r][e+2] = f2u(v.z); tl[r][e+3] = f2u(v.w);
  }
  __syncthreads();
  #pragma unroll
  for (int it = 0; it < 12; ++it) {
    int idx = tid * 4 + it * 1024;
    int e = idx >> 6, nl = idx & 63;
    ushort4 o;
    o.x = tl[nl][e]; o.y = tl[nl+1][e]; o.z = tl[nl+2][e]; o.w = tl[nl+3][e];
    *(ushort4*)(vT + ((size_t)bh * E3n + e) * Nn + n0 + nl) = o;
  }
}

// ================= K6: MFMA ctx = (qf@S_pre + qk@v) / d ==================
__global__ __launch_bounds__(256) void k_ctx_mfma(
    const unsigned short* __restrict__ qf,
    const unsigned short* __restrict__ qkm,
    const unsigned short* __restrict__ ST,   // [blk][192][272]
    const unsigned short* __restrict__ vT,   // [bh][192][2048]
    const float* __restrict__ dden,
    float* __restrict__ ctx) {
  __shared__ unsigned short at[128][40];
  __shared__ unsigned short bt[64][40];
  __shared__ float dd[128];
  int blk = blockIdx.x, ey = blockIdx.y;
  int bh = blk >> 4, c = blk & 15;
  int e0 = ey * 64;
  int tid = threadIdx.x;
  int w = tid >> 6, l = tid & 63;
  int l16 = l & 15, lg = l >> 4;
  size_t qbase = ((size_t)bh * Nn + (size_t)c * Cn) * MPn;
  size_t sbase = (size_t)blk * MPn * E3n + (size_t)e0 * MPn;
  size_t rbase = (size_t)bh * Nn + (size_t)c * Cn;
  if (tid < 128) dd[tid] = dden[rbase + tid];

  f32x4 acc[2][4] = {};
  // phase 1: qf[128x272] @ S^T -> 9 K-steps of 32
  for (int kt = 0; kt < 9; ++kt) {
    int mt = kt * 32;
    __syncthreads();
    #pragma unroll
    for (int p = 0; p < 2; ++p) {
      int idx = tid * 8 + p * 2048;
      int r = idx >> 5, kk = idx & 31;
      uint4 v = make_uint4(0u,0u,0u,0u);
      if (mt + kk < MPn) v = *(const uint4*)(qf + qbase + (size_t)r * MPn + mt + kk);
      *(uint4*)((char*)&at[0][0] + r * 80 + kk * 2) = v;
    }
    {
      int r = tid >> 2, kk = (tid & 3) * 8;
      uint4 v = make_uint4(0u,0u,0u,0u);
      if (mt + kk < MPn) v = *(const uint4*)(ST + sbase + (size_t)r * MPn + mt + kk);
      *(uint4*)((char*)&bt[0][0] + r * 80 + kk * 2) = v;
    }
    __syncthreads();
    bf16x8 a0 = *(const bf16x8*)((const char*)&at[0][0] + (w*32 + l16) * 80 + lg * 16);
    bf16x8 a1 = *(const bf16x8*)((const char*)&at[0][0] + (w*32 + 16 + l16) * 80 + lg * 16);
    #pragma unroll
    for (int ct = 0; ct < 4; ++ct) {
      bf16x8 b = *(const bf16x8*)((const char*)&bt[0][0] + (ct*16 + l16) * 80 + lg * 16);
      acc[0][ct] = __builtin_amdgcn_mfma_f32_16x16x32_bf16(a0, b, acc[0][ct], 0, 0, 0);
      acc[1][ct] = __builtin_amdgcn_mfma_f32_16x16x32_bf16(a1, b, acc[1][ct], 0, 0, 0);
    }
  }
  // phase 2: qk[128x128] @ vT -> 4 K-steps of 32
  size_t kkbase = (size_t)blk * (Cn * Cn);
  size_t vbase = ((size_t)bh * E3n + e0) * Nn + (size_t)c * Cn;
  for (int kt = 0; kt < 4; ++kt) {
    int jt = kt * 32;
    __syncthreads();
    #pragma unroll
    for (int p = 0; p < 2; ++p) {
      int idx = tid * 8 + p * 2048;
      int r = idx >> 5, kk = idx & 31;
      uint4 v = *(const uint4*)(qkm + kkbase + (size_t)r * Cn + jt + kk);
      *(uint4*)((char*)&at[0][0] + r * 80 + kk * 2) = v;
    }
    {
      int r = tid >> 2, kk = (tid & 3) * 8;
      uint4 v = *(const uint4*)(vT + vbase + (size_t)r * Nn + jt + kk);
      *(uint4*)((char*)&bt[0][0] + r * 80 + kk * 2) = v;
    }
    __syncthreads();
    bf16x8 a0 = *(const bf16x8*)((const char*)&at[0][0] + (w*32 + l16) * 80 + lg * 16);
    bf16x8 a1 = *(const bf16x8*)((const char*)&at[0][0] + (w*32 + 16 + l16) * 80 + lg * 16);
    #pragma unroll
    for (int ct = 0; ct < 4; ++ct) {
      bf16x8 b = *(const bf16x8*)((const char*)&bt[0][0] + (ct*16 + l16) * 80 + lg * 16);
      acc[0][ct] = __builtin_amdgcn_mfma_f32_16x16x32_bf16(a0, b, acc[0][ct], 0, 0, 0);
      acc[1][ct] = __builtin_amdgcn_mfma_f32_16x16x32_bf16(a1, b, acc[1][ct], 0, 0, 0);
    }
  }
  // epilogue: divide by denominator, write f32
  #pragma unroll
  for (int rt = 0; rt < 2; ++rt)
    #pragma unroll
    for (int ct = 0; ct < 4; ++ct)
      #pragma unroll
      for (int reg = 0; reg < 4; ++reg) {
        int row = w*32 + rt*16 + lg*4 + reg;
        float inv = 1.f / dd[row];
        ctx[(rbase + row) * (size_t)E3n + e0 + ct*16 + l16] = acc[rt][ct][reg] * inv;
      }
}

// ================= K7a: h = GELU(LN(ctx @ enc_w + enc_b)) -> bf16 ==================
__global__ __launch_bounds__(256) void k_enc(const float* __restrict__ ctx,
    const float* __restrict__ enc_w, const float* __restrict__ enc_b,
    const float* __restrict__ ln_g, const float* __restrict__ ln_b,
    unsigned short* __restrict__ h) {
  __shared__ float ct[64][200];
  int tid = threadIdx.x;
  int r0 = blockIdx.x * 64;
  #pragma unroll
  for (int it = 0; it < 12; ++it) {
    int idx = tid * 4 + it * 1024;
    int row = idx / 192, e = idx % 192;
    float4 v = *(const float4*)(ctx + (size_t)(r0 + row) * E3n + e);
    *(float4*)&ct[row][e] = v;
  }
  __syncthreads();
  int tx = tid & 15, ty = tid >> 4;
  float acc[4][8] = {};
  #pragma unroll 2
  for (int e = 0; e < E3n; ++e) {
    float4 w0 = *(const float4*)(enc_w + (size_t)e * DHn + tx * 8);
    float4 w1 = *(const float4*)(enc_w + (size_t)e * DHn + tx * 8 + 4);
    float w[8] = {w0.x, w0.y, w0.z, w0.w, w1.x, w1.y, w1.z, w1.w};
    #pragma unroll
    for (int i = 0; i < 4; ++i) {
      float a = ct[ty + 16 * i][e];
      #pragma unroll
      for (int j = 0; j < 8; ++j) acc[i][j] += a * w[j];
    }
  }
  float4 b0 = *(const float4*)(enc_b + tx * 8);
  float4 b1 = *(const float4*)(enc_b + tx * 8 + 4);
  float bb[8] = {b0.x, b0.y, b0.z, b0.w, b1.x, b1.y, b1.z, b1.w};
  float4 g0 = *(const float4*)(ln_g + tx * 8);
  float4 g1 = *(const float4*)(ln_g + tx * 8 + 4);
  float gg[8] = {g0.x, g0.y, g0.z, g0.w, g1.x, g1.y, g1.z, g1.w};
  float4 l0 = *(const float4*)(ln_b + tx * 8);
  float4 l1 = *(const float4*)(ln_b + tx * 8 + 4);
  float ll[8] = {l0.x, l0.y, l0.z, l0.w, l1.x, l1.y, l1.z, l1.w};
  #pragma unroll
  for (int i = 0; i < 4; ++i) {
    float s = 0.f, s2 = 0.f;
    #pragma unroll
    for (int j = 0; j < 8; ++j) {
      acc[i][j] += bb[j];
      s += acc[i][j]; s2 += acc[i][j] * acc[i][j];
    }
    #pragma unroll
    for (int m = 1; m < 16; m <<= 1) {
      s += __shfl_xor(s, m);
      s2 += __shfl_xor(s2, m);
    }
    float mu = s * (1.f / 128.f);
    float var = s2 * (1.f / 128.f) - mu * mu;
    float rs = rsqrtf(var + LNEPS);
    uint4 o;
    unsigned int* op = (unsigned int*)&o;
    #pragma unroll
    for (int j2 = 0; j2 < 4; ++j2) {
      float v0 = (acc[i][2 * j2] - mu) * rs * gg[2 * j2] + ll[2 * j2];
      float v1 = (acc[i][2 * j2 + 1] - mu) * rs * gg[2 * j2 + 1] + ll[2 * j2 + 1];
      v0 = 0.5f * v0 * (1.f + erff(v0 * 0.70710678118654752f));
      v1 = 0.5f * v1 * (1.f + erff(v1 * 0.70710678118654752f));
      op[j2] = pack2(v0, v1);
    }
    *(uint4*)(h + (size_t)(r0 + ty + 16 * i) * DHn + tx * 8) = o;
  }
}

// ================= K7b: probs = softmax(h @ dec_w + dec_b) ==================
__global__ __launch_bounds__(256) void k_dec(const unsigned short* __restrict__ h,
    const float* __restrict__ dec_w, const float* __restrict__ dec_b,
    float* __restrict__ probs) {
  __shared__ float ht[64][136];
  int tid = threadIdx.x;
  int r0 = blockIdx.x * 64;
  #pragma unroll
  for (int it = 0; it < 4; ++it) {
    int idx = tid * 8 + it * 2048;
    int row = idx >> 7, c = idx & 127;
    uint4 u = *(const uint4*)(h + (size_t)(r0 + row) * DHn + c);
    float a[8]; unpack8(u, a);
    *(float4*)&ht[row][c] = make_float4(a[0], a[1], a[2], a[3]);
    *(float4*)&ht[row][c + 4] = make_float4(a[4], a[5], a[6], a[7]);
  }
  __syncthreads();
  int tx = tid & 15, ty = tid >> 4;
  float acc[4][8] = {};
  #pragma unroll 2
  for (int c = 0; c < DHn; ++c) {
    float4 w0 = *(const float4*)(dec_w + (size_t)c * Tn + tx * 8);
    float4 w1 = *(const float4*)(dec_w + (size_t)c * Tn + tx * 8 + 4);
    float w[8] = {w0.x, w0.y, w0.z, w0.w, w1.x, w1.y, w1.z, w1.w};
    #pragma unroll
    for (int i = 0; i < 4; ++i) {
      float a = ht[ty + 16 * i][c];
      #pragma unroll
      for (int j = 0; j < 8; ++j) acc[i][j] += a * w[j];
    }
  }
  float4 b0 = *(const float4*)(dec_b + tx * 8);
  float4 b1 = *(const float4*)(dec_b + tx * 8 + 4);
  float bb[8] = {b0.x, b0.y, b0.z, b0.w, b1.x, b1.y, b1.z, b1.w};
  #pragma unroll
  for (int i = 0; i < 4; ++i) {
    float m = -1e30f;
    #pragma unroll
    for (int j = 0; j < 8; ++j) {
      acc[i][j] += bb[j];
      m = fmaxf(m, acc[i][j]);
    }
    #pragma unroll
    for (int mm = 1; mm < 16; mm <<= 1) m = fmaxf(m, __shfl_xor(m, mm));
    float s = 0.f;
    #pragma unroll
    for (int j = 0; j < 8; ++j) { acc[i][j] = expf(acc[i][j] - m); s += acc[i][j]; }
    #pragma unroll
    for (int mm = 1; mm < 16; mm <<= 1) s += __shfl_xor(s, mm);
    float inv = 1.f / s;
    float4 oa = {acc[i][0] * inv, acc[i][1] * inv, acc[i][2] * inv, acc[i][3] * inv};
    float4 ob = {acc[i][4] * inv, acc[i][5] * inv, acc[i][6] * inv, acc[i][7] * inv};
    size_t base = (size_t)(r0 + ty + 16 * i) * Tn + tx * 8;
    *(float4*)(probs + base) = oa;
    *(float4*)(probs + base + 4) = ob;
  }
}

// ================= launch ==================
extern "C" void kernel_launch(void* const* d_in, const int* in_sizes, int n_in,
                              void* d_out, int out_size, void* d_ws, size_t ws_size,
                              hipStream_t stream) {
  const float* q     = (const float*)d_in[0];
  const float* k     = (const float*)d_in[1];
  const float* v3    = (const float*)d_in[2];
  const float* proj  = (const float*)d_in[3];
  const float* enc_w = (const float*)d_in[4];
  const float* enc_b = (const float*)d_in[5];
  const float* ln_g  = (const float*)d_in[6];
  const float* ln_b  = (const float*)d_in[7];
  const float* dec_w = (const float*)d_in[8];
  const float* dec_b = (const float*)d_in[9];
  float* out = (float*)d_out;
  char* ws = (char*)d_ws;
  if (ws_size < WS_NEED) return;

  unsigned short* qf   = (unsigned short*)(ws + OFF_QF);
  unsigned short* kf   = (unsigned short*)(ws + OFF_KF);
  unsigned short* qk   = (unsigned short*)(ws + OFF_QK);
  float*          dden = (float*)(ws + OFF_D);
  float*          kpre = (float*)(ws + OFF_KPRE);
  unsigned short* ST   = (unsigned short*)(ws + OFF_S);
  unsigned short* vT   = (unsigned short*)(ws + OFF_VT);  // aliases kf (dead after k_schunk)
  unsigned short* hbuf = (unsigned short*)(ws + OFF_H);   // aliases qf (dead after k_ctx)
  float* ctx   = out;
  float* probs = out + (size_t)BHn * Nn * E3n;

  k_features<<<dim3(BHn * Nn / 64, 2), 256, 0, stream>>>(q, k, proj, qf, kf);
  k_ksum    <<<dim3(BHn * NCn),       256, 0, stream>>>(kf, kpre);
  k_kprefix <<<dim3(BHn),             256, 0, stream>>>(kpre);
  k_qk_mfma <<<dim3(BHn * NCn),       256, 0, stream>>>(qf, kf, kpre, qk, dden);
  k_schunk  <<<dim3(BHn * NCn, 3),    256, 0, stream>>>(kf, v3, ST);
  k_vt      <<<dim3(BHn * 32),        256, 0, stream>>>(v3, vT);
  k_sprefix <<<dim3(BHn * 51),        256, 0, stream>>>(ST);
  k_ctx_mfma<<<dim3(BHn * NCn, 3),    256, 0, stream>>>(qf, qk, ST, vT, dden, ctx);
  k_enc     <<<dim3(BHn * Nn / 64),   256, 0, stream>>>(ctx, enc_w, enc_b, ln_g, ln_b, hbuf);
  k_dec     <<<dim3(BHn * Nn / 64),   256, 0, stream>>>(hbuf, dec_w, dec_b, probs);
}

// Round 4
// 254.280 us; speedup vs baseline: 2.1699x; 1.3126x over previous
//
#include <hip/hip_runtime.h>
#include <hip/hip_bf16.h>
#include <math.h>

// ---------------- problem constants ----------------
constexpr int Bn = 2, Hn = 12, BHn = 24;
constexpr int Nn = 2048, Dn = 64;
constexpr int Mn = 266, MPn = 272;          // M padded to 272 (zero-filled)
constexpr int E3n = 192, DHn = 128, Tn = 128;
constexpr int Cn = 128, NCn = 16;           // chunking

#define DNRM 0.35355339059327373f   // 64^-0.25
#define KEPS 1e-3f
#define DEPS 1e-6f
#define LNEPS 1e-5f

// ---------------- ws layout (bytes) ----------------
static const size_t OFF_QF   = 0;            // bf16 [BH][N][MP]   26,738,688
static const size_t OFF_KF   = 26738688;     // bf16 [BH][N][MP]
static const size_t OFF_QK   = 53477376;     // bf16 [BH][NC][C][C] 12,582,912
static const size_t OFF_D    = 66060288;     // f32  [BH][N]          196,608
static const size_t OFF_KPRE = 66256896;     // f32  [BH][NC][MP]     417,792
static const size_t OFF_S    = 66674688;     // bf16 [BH][NC][192][272] (S^T) 40,108,032
static const size_t OFF_H    = OFF_QF;       // bf16 [BH*N][128] (aliases qf; dead after k_ctx)
static const size_t WS_NEED  = 106782720;

// ---------------- helpers ----------------
using bf16x8 = __attribute__((ext_vector_type(8))) short;
using f32x4  = __attribute__((ext_vector_type(4))) float;

__device__ inline float u2f(unsigned int u) {
  union { float f; unsigned int i; } c; c.i = u << 16; return c.f;
}
__device__ inline unsigned short f2u(float x) {
  __hip_bfloat16 h = __float2bfloat16(x);
  unsigned short u; __builtin_memcpy(&u, &h, 2); return u;
}
__device__ inline unsigned int pack2(float lo, float hi) {
  return (unsigned int)f2u(lo) | ((unsigned int)f2u(hi) << 16);
}
__device__ inline void unpack8(uint4 v, float* a) {
  a[0] = u2f(v.x & 0xffffu); a[1] = u2f(v.x >> 16);
  a[2] = u2f(v.y & 0xffffu); a[3] = u2f(v.y >> 16);
  a[4] = u2f(v.z & 0xffffu); a[5] = u2f(v.z >> 16);
  a[6] = u2f(v.w & 0xffffu); a[7] = u2f(v.w >> 16);
}

// ================= K1: performer features ==================
__global__ __launch_bounds__(256) void k_features(
    const float* __restrict__ q, const float* __restrict__ k,
    const float* __restrict__ proj,
    unsigned short* __restrict__ qf, unsigned short* __restrict__ kf) {
  __shared__ float xt[64][68];   // [k][row]
  __shared__ float pt[64][68];   // [k][col]
  const float* x = (blockIdx.y == 0) ? q : k;
  unsigned short* outp = (blockIdx.y == 0) ? qf : kf;
  int tid = threadIdx.x;
  int r0 = blockIdx.x * 64;
  for (int idx = tid * 4; idx < 4096; idx += 1024) {
    int row = idx >> 6, kk = idx & 63;
    float4 v = *(const float4*)(x + (size_t)(r0 + row) * Dn + kk);
    xt[kk][row] = v.x; xt[kk+1][row] = v.y; xt[kk+2][row] = v.z; xt[kk+3][row] = v.w;
  }
  int tx = tid & 15, ty = tid >> 4;
  int rr = ty * 4, cc = tx * 4;
  for (int ct = 0; ct < 5; ++ct) {
    int c0 = ct * 64;
    __syncthreads();
    for (int idx = tid * 4; idx < 4096; idx += 1024) {
      int col = idx >> 6, kk = idx & 63;
      int p = c0 + col;
      float4 v = make_float4(0.f, 0.f, 0.f, 0.f);
      if (p < Mn) v = *(const float4*)(proj + (size_t)p * Dn + kk);
      pt[kk][col] = v.x; pt[kk+1][col] = v.y; pt[kk+2][col] = v.z; pt[kk+3][col] = v.w;
    }
    __syncthreads();
    float acc[4][4] = {};
    #pragma unroll 8
    for (int kk = 0; kk < 64; ++kk) {
      float4 av = *(const float4*)&xt[kk][rr];
      float4 bv = *(const float4*)&pt[kk][cc];
      float a[4] = {av.x, av.y, av.z, av.w};
      float b[4] = {bv.x, bv.y, bv.z, bv.w};
      #pragma unroll
      for (int i = 0; i < 4; ++i)
        #pragma unroll
        for (int j = 0; j < 4; ++j) acc[i][j] += a[i] * b[j];
    }
    int m0w = c0 + cc;
    if (m0w < MPn) {
      #pragma unroll
      for (int r = 0; r < 4; ++r) {
        int row = r0 + rr + r;
        ushort4 o;
        unsigned short* op = (unsigned short*)&o;
        #pragma unroll
        for (int s = 0; s < 4; ++s) {
          int m = m0w + s;
          float val = 0.f;
          if (m < Mn) val = fmaxf(acc[r][s] * DNRM, 0.f) + KEPS;
          op[s] = f2u(val);
        }
        *(ushort4*)(outp + (size_t)row * MPn + m0w) = o;
      }
    }
  }
}

// ================= K2a: per-chunk kf column sums ==================
__global__ __launch_bounds__(256) void k_ksum(const unsigned short* __restrict__ kf,
                                              float* __restrict__ kpre) {
  int blk = blockIdx.x; int bh = blk >> 4, c = blk & 15;
  int tid = threadIdx.x;
  for (int m = tid; m < MPn; m += 256) {
    const unsigned short* base = kf + ((size_t)bh * Nn + (size_t)c * Cn) * MPn + m;
    float s = 0.f;
    #pragma unroll 8
    for (int j = 0; j < Cn; ++j) s += u2f(base[(size_t)j * MPn]);
    kpre[((size_t)bh * NCn + c) * MPn + m] = s;
  }
}

// ================= K2b: in-place exclusive prefix over chunks ==================
__global__ __launch_bounds__(256) void k_kprefix(float* __restrict__ kpre) {
  int bh = blockIdx.x; int tid = threadIdx.x;
  for (int m = tid; m < MPn; m += 256) {
    float v[NCn];
    #pragma unroll
    for (int c = 0; c < NCn; ++c) v[c] = kpre[((size_t)bh * NCn + c) * MPn + m];
    float acc = 0.f;
    #pragma unroll
    for (int c = 0; c < NCn; ++c) {
      kpre[((size_t)bh * NCn + c) * MPn + m] = acc;
      acc += v[c];
    }
  }
}

// ================= K3: MFMA masked qk + denominator ==================
__global__ __launch_bounds__(256) void k_qk_mfma(
    const unsigned short* __restrict__ qf,
    const unsigned short* __restrict__ kf,
    const float* __restrict__ kpre,
    unsigned short* __restrict__ qkout,
    float* __restrict__ dden) {
  __shared__ unsigned short at[128][40];   // qf tile, pad-40 (conflict-free)
  __shared__ unsigned short ktl[128][40];  // kf tile
  __shared__ float kp[MPn];
  __shared__ float rs_lds[128];
  int blk = blockIdx.x;
  int bh = blk >> 4, c = blk & 15;
  int tid = threadIdx.x;
  int w = tid >> 6, l = tid & 63;
  int l16 = l & 15, lg = l >> 4;
  size_t qbase = ((size_t)bh * Nn + (size_t)c * Cn) * MPn;
  size_t rbase = (size_t)bh * Nn + (size_t)c * Cn;
  for (int m = tid; m < MPn; m += 256) kp[m] = kpre[((size_t)bh * NCn + c) * MPn + m];

  f32x4 acc[2][8] = {};
  for (int kt = 0; kt < 9; ++kt) {
    int mt = kt * 32;
    __syncthreads();
    #pragma unroll
    for (int p = 0; p < 2; ++p) {
      int idx = tid * 8 + p * 2048;
      int r = idx >> 5, kk = idx & 31;
      uint4 va = make_uint4(0u,0u,0u,0u), vk = make_uint4(0u,0u,0u,0u);
      if (mt + kk < MPn) {
        va = *(const uint4*)(qf + qbase + (size_t)r * MPn + mt + kk);
        vk = *(const uint4*)(kf + qbase + (size_t)r * MPn + mt + kk);
      }
      *(uint4*)((char*)&at[0][0] + r * 80 + kk * 2) = va;
      *(uint4*)((char*)&ktl[0][0] + r * 80 + kk * 2) = vk;
    }
    __syncthreads();
    bf16x8 a0 = *(const bf16x8*)((const char*)&at[0][0] + (w*32 + l16) * 80 + lg * 16);
    bf16x8 a1 = *(const bf16x8*)((const char*)&at[0][0] + (w*32 + 16 + l16) * 80 + lg * 16);
    #pragma unroll
    for (int ct = 0; ct < 8; ++ct) {
      bf16x8 b = *(const bf16x8*)((const char*)&ktl[0][0] + (ct*16 + l16) * 80 + lg * 16);
      acc[0][ct] = __builtin_amdgcn_mfma_f32_16x16x32_bf16(a0, b, acc[0][ct], 0, 0, 0);
      acc[1][ct] = __builtin_amdgcn_mfma_f32_16x16x32_bf16(a1, b, acc[1][ct], 0, 0, 0);
    }
  }
  size_t qkbase = (size_t)blk * (Cn * Cn);
  float rs[2][4] = {};
  #pragma unroll
  for (int rt = 0; rt < 2; ++rt)
    #pragma unroll
    for (int ct = 0; ct < 8; ++ct)
      #pragma unroll
      for (int reg = 0; reg < 4; ++reg) {
        int row = w*32 + rt*16 + lg*4 + reg;
        int col = ct*16 + l16;
        float v = (col <= row) ? acc[rt][ct][reg] : 0.f;
        qkout[qkbase + (size_t)row * Cn + col] = f2u(v);
        rs[rt][reg] += v;
      }
  #pragma unroll
  for (int rt = 0; rt < 2; ++rt)
    #pragma unroll
    for (int reg = 0; reg < 4; ++reg) {
      float s = rs[rt][reg];
      s += __shfl_xor(s, 1); s += __shfl_xor(s, 2);
      s += __shfl_xor(s, 4); s += __shfl_xor(s, 8);
      rs[rt][reg] = s;
    }
  if (l16 == 0) {
    #pragma unroll
    for (int rt = 0; rt < 2; ++rt)
      #pragma unroll
      for (int reg = 0; reg < 4; ++reg)
        rs_lds[w*32 + rt*16 + lg*4 + reg] = rs[rt][reg];
  }
  __syncthreads();
  if (tid < 128) {
    float dot = 0.f, qs = 0.f;
    const unsigned short* qrow = qf + qbase + (size_t)tid * MPn;
    for (int m = 0; m < MPn; m += 8) {
      uint4 v = *(const uint4*)(qrow + m);
      float a[8]; unpack8(v, a);
      #pragma unroll
      for (int t = 0; t < 8; ++t) { dot += a[t] * kp[m + t]; qs += a[t]; }
    }
    dden[rbase + tid] = rs_lds[tid] + dot + DEPS * qs;
  }
}

// ================= K4: MFMA per-chunk S^T_c[e][m] = sum_j v[j][e]*kf[j][m] =========
// A = v^T (transposed+bf16-converted in LDS from f32 v3), B = kf^T (transposed in LDS)
__global__ __launch_bounds__(256) void k_schunk_mfma(
    const unsigned short* __restrict__ kf,
    const float* __restrict__ v3,
    unsigned short* __restrict__ ST) {
  __shared__ unsigned short at[64][40];    // v^T tile  [e-local][j-local]
  __shared__ unsigned short bt[272][40];   // kf^T tile [m][j-local]
  int blk = blockIdx.x, ey = blockIdx.y;
  int bh = blk >> 4, c = blk & 15;
  int e0 = ey * 64;
  int tid = threadIdx.x;
  int w = tid >> 6, l = tid & 63;
  int l16 = l & 15, lg = l >> 4;
  size_t vbase = ((size_t)bh * Nn + (size_t)c * Cn) * E3n + e0;
  size_t kbase = ((size_t)bh * Nn + (size_t)c * Cn) * MPn;

  f32x4 acc[17] = {};
  for (int kt = 0; kt < 4; ++kt) {
    int jt = kt * 32;
    __syncthreads();
    // stage A: at[e][j] = bf16(v3[jt+j][e0+e]); lanes vary j -> 2B stride, conflict-free
    #pragma unroll
    for (int p = 0; p < 2; ++p) {
      int idx = tid + p * 256;
      int j = idx & 31, eq = idx >> 5;
      float4 v = *(const float4*)(v3 + vbase + (size_t)(jt + j) * E3n + eq * 4);
      at[eq*4+0][j] = f2u(v.x); at[eq*4+1][j] = f2u(v.y);
      at[eq*4+2][j] = f2u(v.z); at[eq*4+3][j] = f2u(v.w);
    }
    // stage B: bt[m][j] = kf[jt+j][m]; 1088 uint4 loads, lanes vary j on write
    for (int idx = tid; idx < 1088; idx += 256) {
      int j = idx & 31, mq = idx >> 5;
      uint4 v = *(const uint4*)(kf + kbase + (size_t)(jt + j) * MPn + mq * 8);
      unsigned short tmp[8]; __builtin_memcpy(tmp, &v, 16);
      #pragma unroll
      for (int t = 0; t < 8; ++t) bt[mq*8+t][j] = tmp[t];
    }
    __syncthreads();
    bf16x8 a = *(const bf16x8*)((const char*)&at[0][0] + (w*16 + l16) * 80 + lg * 16);
    #pragma unroll
    for (int ct = 0; ct < 17; ++ct) {
      bf16x8 b = *(const bf16x8*)((const char*)&bt[0][0] + (ct*16 + l16) * 80 + lg * 16);
      acc[ct] = __builtin_amdgcn_mfma_f32_16x16x32_bf16(a, b, acc[ct], 0, 0, 0);
    }
  }
  // epilogue: ST[e][m] bf16
  size_t stbase = (size_t)blk * MPn * E3n + (size_t)e0 * MPn;
  #pragma unroll
  for (int ct = 0; ct < 17; ++ct)
    #pragma unroll
    for (int reg = 0; reg < 4; ++reg) {
      int e_loc = w*16 + lg*4 + reg;
      ST[stbase + (size_t)e_loc * MPn + ct*16 + l16] = f2u(acc[ct][reg]);
    }
}

// ================= K5: in-place exclusive prefix of S^T over chunks (flat) ==========
__global__ __launch_bounds__(256) void k_sprefix(unsigned short* __restrict__ S) {
  int bh = blockIdx.x / 51, sub = blockIdx.x % 51;
  int idx4 = sub * 256 + threadIdx.x;          // 51*256 == MPn*E3n/4 exactly
  size_t off = (size_t)idx4 * 4;
  ushort4 v[NCn];
  #pragma unroll
  for (int c = 0; c < NCn; ++c)
    v[c] = *(const ushort4*)(S + ((size_t)(bh * NCn + c)) * MPn * E3n + off);
  float a0 = 0.f, a1 = 0.f, a2 = 0.f, a3 = 0.f;
  #pragma unroll
  for (int c = 0; c < NCn; ++c) {
    ushort4 o;
    unsigned short* op = (unsigned short*)&o;
    op[0] = f2u(a0); op[1] = f2u(a1); op[2] = f2u(a2); op[3] = f2u(a3);
    *(ushort4*)(S + ((size_t)(bh * NCn + c)) * MPn * E3n + off) = o;
    a0 += u2f(v[c].x); a1 += u2f(v[c].y); a2 += u2f(v[c].z); a3 += u2f(v[c].w);
  }
}

// ================= K6: MFMA ctx = (qf@S_pre + qk@v) / d ==================
__global__ __launch_bounds__(256) void k_ctx_mfma(
    const unsigned short* __restrict__ qf,
    const unsigned short* __restrict__ qkm,
    const unsigned short* __restrict__ ST,   // [blk][192][272]
    const float* __restrict__ v3,
    const float* __restrict__ dden,
    float* __restrict__ ctx) {
  __shared__ unsigned short at[128][40];
  __shared__ unsigned short bt[64][40];
  __shared__ float dd[128];
  int blk = blockIdx.x, ey = blockIdx.y;
  int bh = blk >> 4, c = blk & 15;
  int e0 = ey * 64;
  int tid = threadIdx.x;
  int w = tid >> 6, l = tid & 63;
  int l16 = l & 15, lg = l >> 4;
  size_t qbase = ((size_t)bh * Nn + (size_t)c * Cn) * MPn;
  size_t sbase = (size_t)blk * MPn * E3n + (size_t)e0 * MPn;
  size_t rbase = (size_t)bh * Nn + (size_t)c * Cn;
  if (tid < 128) dd[tid] = dden[rbase + tid];

  f32x4 acc[2][4] = {};
  // phase 1: qf[128x272] @ S^T -> 9 K-steps of 32
  for (int kt = 0; kt < 9; ++kt) {
    int mt = kt * 32;
    __syncthreads();
    #pragma unroll
    for (int p = 0; p < 2; ++p) {
      int idx = tid * 8 + p * 2048;
      int r = idx >> 5, kk = idx & 31;
      uint4 v = make_uint4(0u,0u,0u,0u);
      if (mt + kk < MPn) v = *(const uint4*)(qf + qbase + (size_t)r * MPn + mt + kk);
      *(uint4*)((char*)&at[0][0] + r * 80 + kk * 2) = v;
    }
    {
      int r = tid >> 2, kk = (tid & 3) * 8;
      uint4 v = make_uint4(0u,0u,0u,0u);
      if (mt + kk < MPn) v = *(const uint4*)(ST + sbase + (size_t)r * MPn + mt + kk);
      *(uint4*)((char*)&bt[0][0] + r * 80 + kk * 2) = v;
    }
    __syncthreads();
    bf16x8 a0 = *(const bf16x8*)((const char*)&at[0][0] + (w*32 + l16) * 80 + lg * 16);
    bf16x8 a1 = *(const bf16x8*)((const char*)&at[0][0] + (w*32 + 16 + l16) * 80 + lg * 16);
    #pragma unroll
    for (int ct = 0; ct < 4; ++ct) {
      bf16x8 b = *(const bf16x8*)((const char*)&bt[0][0] + (ct*16 + l16) * 80 + lg * 16);
      acc[0][ct] = __builtin_amdgcn_mfma_f32_16x16x32_bf16(a0, b, acc[0][ct], 0, 0, 0);
      acc[1][ct] = __builtin_amdgcn_mfma_f32_16x16x32_bf16(a1, b, acc[1][ct], 0, 0, 0);
    }
  }
  // phase 2: qk[128x128] @ v -> 4 K-steps of 32; B staged by transposing f32 v3
  size_t kkbase = (size_t)blk * (Cn * Cn);
  size_t vb3 = ((size_t)bh * Nn + (size_t)c * Cn) * E3n + e0;
  for (int kt = 0; kt < 4; ++kt) {
    int jt = kt * 32;
    __syncthreads();
    #pragma unroll
    for (int p = 0; p < 2; ++p) {
      int idx = tid * 8 + p * 2048;
      int r = idx >> 5, kk = idx & 31;
      uint4 v = *(const uint4*)(qkm + kkbase + (size_t)r * Cn + jt + kk);
      *(uint4*)((char*)&at[0][0] + r * 80 + kk * 2) = v;
    }
    #pragma unroll
    for (int p = 0; p < 2; ++p) {
      int idx = tid + p * 256;
      int j = idx & 31, eq = idx >> 5;
      float4 v = *(const float4*)(v3 + vb3 + (size_t)(jt + j) * E3n + eq * 4);
      bt[eq*4+0][j] = f2u(v.x); bt[eq*4+1][j] = f2u(v.y);
      bt[eq*4+2][j] = f2u(v.z); bt[eq*4+3][j] = f2u(v.w);
    }
    __syncthreads();
    bf16x8 a0 = *(const bf16x8*)((const char*)&at[0][0] + (w*32 + l16) * 80 + lg * 16);
    bf16x8 a1 = *(const bf16x8*)((const char*)&at[0][0] + (w*32 + 16 + l16) * 80 + lg * 16);
    #pragma unroll
    for (int ct = 0; ct < 4; ++ct) {
      bf16x8 b = *(const bf16x8*)((const char*)&bt[0][0] + (ct*16 + l16) * 80 + lg * 16);
      acc[0][ct] = __builtin_amdgcn_mfma_f32_16x16x32_bf16(a0, b, acc[0][ct], 0, 0, 0);
      acc[1][ct] = __builtin_amdgcn_mfma_f32_16x16x32_bf16(a1, b, acc[1][ct], 0, 0, 0);
    }
  }
  #pragma unroll
  for (int rt = 0; rt < 2; ++rt)
    #pragma unroll
    for (int ct = 0; ct < 4; ++ct)
      #pragma unroll
      for (int reg = 0; reg < 4; ++reg) {
        int row = w*32 + rt*16 + lg*4 + reg;
        float inv = 1.f / dd[row];
        ctx[(rbase + row) * (size_t)E3n + e0 + ct*16 + l16] = acc[rt][ct][reg] * inv;
      }
}

// ================= K7a: h = GELU(LN(ctx @ enc_w + enc_b)) -> bf16 ==================
__global__ __launch_bounds__(256) void k_enc(const float* __restrict__ ctx,
    const float* __restrict__ enc_w, const float* __restrict__ enc_b,
    const float* __restrict__ ln_g, const float* __restrict__ ln_b,
    unsigned short* __restrict__ h) {
  __shared__ float ct[64][200];
  int tid = threadIdx.x;
  int r0 = blockIdx.x * 64;
  #pragma unroll
  for (int it = 0; it < 12; ++it) {
    int idx = tid * 4 + it * 1024;
    int row = idx / 192, e = idx % 192;
    float4 v = *(const float4*)(ctx + (size_t)(r0 + row) * E3n + e);
    *(float4*)&ct[row][e] = v;
  }
  __syncthreads();
  int tx = tid & 15, ty = tid >> 4;
  float acc[4][8] = {};
  #pragma unroll 2
  for (int e = 0; e < E3n; ++e) {
    float4 w0 = *(const float4*)(enc_w + (size_t)e * DHn + tx * 8);
    float4 w1 = *(const float4*)(enc_w + (size_t)e * DHn + tx * 8 + 4);
    float w[8] = {w0.x, w0.y, w0.z, w0.w, w1.x, w1.y, w1.z, w1.w};
    #pragma unroll
    for (int i = 0; i < 4; ++i) {
      float a = ct[ty + 16 * i][e];
      #pragma unroll
      for (int j = 0; j < 8; ++j) acc[i][j] += a * w[j];
    }
  }
  float4 b0 = *(const float4*)(enc_b + tx * 8);
  float4 b1 = *(const float4*)(enc_b + tx * 8 + 4);
  float bb[8] = {b0.x, b0.y, b0.z, b0.w, b1.x, b1.y, b1.z, b1.w};
  float4 g0 = *(const float4*)(ln_g + tx * 8);
  float4 g1 = *(const float4*)(ln_g + tx * 8 + 4);
  float gg[8] = {g0.x, g0.y, g0.z, g0.w, g1.x, g1.y, g1.z, g1.w};
  float4 l0 = *(const float4*)(ln_b + tx * 8);
  float4 l1 = *(const float4*)(ln_b + tx * 8 + 4);
  float ll[8] = {l0.x, l0.y, l0.z, l0.w, l1.x, l1.y, l1.z, l1.w};
  #pragma unroll
  for (int i = 0; i < 4; ++i) {
    float s = 0.f, s2 = 0.f;
    #pragma unroll
    for (int j = 0; j < 8; ++j) {
      acc[i][j] += bb[j];
      s += acc[i][j]; s2 += acc[i][j] * acc[i][j];
    }
    #pragma unroll
    for (int m = 1; m < 16; m <<= 1) {
      s += __shfl_xor(s, m);
      s2 += __shfl_xor(s2, m);
    }
    float mu = s * (1.f / 128.f);
    float var = s2 * (1.f / 128.f) - mu * mu;
    float rs = rsqrtf(var + LNEPS);
    uint4 o;
    unsigned int* op = (unsigned int*)&o;
    #pragma unroll
    for (int j2 = 0; j2 < 4; ++j2) {
      float v0 = (acc[i][2 * j2] - mu) * rs * gg[2 * j2] + ll[2 * j2];
      float v1 = (acc[i][2 * j2 + 1] - mu) * rs * gg[2 * j2 + 1] + ll[2 * j2 + 1];
      v0 = 0.5f * v0 * (1.f + erff(v0 * 0.70710678118654752f));
      v1 = 0.5f * v1 * (1.f + erff(v1 * 0.70710678118654752f));
      op[j2] = pack2(v0, v1);
    }
    *(uint4*)(h + (size_t)(r0 + ty + 16 * i) * DHn + tx * 8) = o;
  }
}

// ================= K7b: probs = softmax(h @ dec_w + dec_b) ==================
__global__ __launch_bounds__(256) void k_dec(const unsigned short* __restrict__ h,
    const float* __restrict__ dec_w, const float* __restrict__ dec_b,
    float* __restrict__ probs) {
  __shared__ float ht[64][136];
  int tid = threadIdx.x;
  int r0 = blockIdx.x * 64;
  #pragma unroll
  for (int it = 0; it < 4; ++it) {
    int idx = tid * 8 + it * 2048;
    int row = idx >> 7, c = idx & 127;
    uint4 u = *(const uint4*)(h + (size_t)(r0 + row) * DHn + c);
    float a[8]; unpack8(u, a);
    *(float4*)&ht[row][c] = make_float4(a[0], a[1], a[2], a[3]);
    *(float4*)&ht[row][c + 4] = make_float4(a[4], a[5], a[6], a[7]);
  }
  __syncthreads();
  int tx = tid & 15, ty = tid >> 4;
  float acc[4][8] = {};
  #pragma unroll 2
  for (int c = 0; c < DHn; ++c) {
    float4 w0 = *(const float4*)(dec_w + (size_t)c * Tn + tx * 8);
    float4 w1 = *(const float4*)(dec_w + (size_t)c * Tn + tx * 8 + 4);
    float w[8] = {w0.x, w0.y, w0.z, w0.w, w1.x, w1.y, w1.z, w1.w};
    #pragma unroll
    for (int i = 0; i < 4; ++i) {
      float a = ht[ty + 16 * i][c];
      #pragma unroll
      for (int j = 0; j < 8; ++j) acc[i][j] += a * w[j];
    }
  }
  float4 b0 = *(const float4*)(dec_b + tx * 8);
  float4 b1 = *(const float4*)(dec_b + tx * 8 + 4);
  float bb[8] = {b0.x, b0.y, b0.z, b0.w, b1.x, b1.y, b1.z, b1.w};
  #pragma unroll
  for (int i = 0; i < 4; ++i) {
    float m = -1e30f;
    #pragma unroll
    for (int j = 0; j < 8; ++j) {
      acc[i][j] += bb[j];
      m = fmaxf(m, acc[i][j]);
    }
    #pragma unroll
    for (int mm = 1; mm < 16; mm <<= 1) m = fmaxf(m, __shfl_xor(m, mm));
    float s = 0.f;
    #pragma unroll
    for (int j = 0; j < 8; ++j) { acc[i][j] = expf(acc[i][j] - m); s += acc[i][j]; }
    #pragma unroll
    for (int mm = 1; mm < 16; mm <<= 1) s += __shfl_xor(s, mm);
    float inv = 1.f / s;
    float4 oa = {acc[i][0] * inv, acc[i][1] * inv, acc[i][2] * inv, acc[i][3] * inv};
    float4 ob = {acc[i][4] * inv, acc[i][5] * inv, acc[i][6] * inv, acc[i][7] * inv};
    size_t base = (size_t)(r0 + ty + 16 * i) * Tn + tx * 8;
    *(float4*)(probs + base) = oa;
    *(float4*)(probs + base + 4) = ob;
  }
}

// ================= launch ==================
extern "C" void kernel_launch(void* const* d_in, const int* in_sizes, int n_in,
                              void* d_out, int out_size, void* d_ws, size_t ws_size,
                              hipStream_t stream) {
  const float* q     = (const float*)d_in[0];
  const float* k     = (const float*)d_in[1];
  const float* v3    = (const float*)d_in[2];
  const float* proj  = (const float*)d_in[3];
  const float* enc_w = (const float*)d_in[4];
  const float* enc_b = (const float*)d_in[5];
  const float* ln_g  = (const float*)d_in[6];
  const float* ln_b  = (const float*)d_in[7];
  const float* dec_w = (const float*)d_in[8];
  const float* dec_b = (const float*)d_in[9];
  float* out = (float*)d_out;
  char* ws = (char*)d_ws;
  if (ws_size < WS_NEED) return;

  unsigned short* qf   = (unsigned short*)(ws + OFF_QF);
  unsigned short* kf   = (unsigned short*)(ws + OFF_KF);
  unsigned short* qk   = (unsigned short*)(ws + OFF_QK);
  float*          dden = (float*)(ws + OFF_D);
  float*          kpre = (float*)(ws + OFF_KPRE);
  unsigned short* ST   = (unsigned short*)(ws + OFF_S);
  unsigned short* hbuf = (unsigned short*)(ws + OFF_H);   // aliases qf (dead after k_ctx)
  float* ctx   = out;
  float* probs = out + (size_t)BHn * Nn * E3n;

  k_features  <<<dim3(BHn * Nn / 64, 2), 256, 0, stream>>>(q, k, proj, qf, kf);
  k_ksum      <<<dim3(BHn * NCn),       256, 0, stream>>>(kf, kpre);
  k_kprefix   <<<dim3(BHn),             256, 0, stream>>>(kpre);
  k_qk_mfma   <<<dim3(BHn * NCn),       256, 0, stream>>>(qf, kf, kpre, qk, dden);
  k_schunk_mfma<<<dim3(BHn * NCn, 3),   256, 0, stream>>>(kf, v3, ST);
  k_sprefix   <<<dim3(BHn * 51),        256, 0, stream>>>(ST);
  k_ctx_mfma  <<<dim3(BHn * NCn, 3),    256, 0, stream>>>(qf, qk, ST, v3, dden, ctx);
  k_enc       <<<dim3(BHn * Nn / 64),   256, 0, stream>>>(ctx, enc_w, enc_b, ln_g, ln_b, hbuf);
  k_dec       <<<dim3(BHn * Nn / 64),   256, 0, stream>>>(hbuf, dec_w, dec_b, probs);
}

// Round 5
// 217.076 us; speedup vs baseline: 2.5418x; 1.1714x over previous
//
#include <hip/hip_runtime.h>
#include <hip/hip_bf16.h>
#include <math.h>

// ---------------- problem constants ----------------
constexpr int Bn = 2, Hn = 12, BHn = 24;
constexpr int Nn = 2048, Dn = 64;
constexpr int Mn = 266, MPn = 272;          // M padded to 272 (zero-filled)
constexpr int E3n = 192, DHn = 128, Tn = 128;
constexpr int Cn = 128, NCn = 16;           // chunking

#define DNRM 0.35355339059327373f   // 64^-0.25
#define KEPS 1e-3f
#define DEPS 1e-6f
#define LNEPS 1e-5f

// ---------------- ws layout (bytes) ----------------
static const size_t OFF_QF   = 0;            // bf16 [BH][N][MP]   26,738,688
static const size_t OFF_KF   = 26738688;     // bf16 [BH][N][MP]
static const size_t OFF_QK   = 53477376;     // bf16 [BH][NC][C][C] 12,582,912
static const size_t OFF_D    = 66060288;     // f32  [BH][N]          196,608
static const size_t OFF_KPRE = 66256896;     // f32  [BH][NC][MP]     417,792
static const size_t OFF_S    = 66674688;     // bf16 [BH][NC][192][272] (S^T) 40,108,032
static const size_t OFF_H    = OFF_QF;       // bf16 [BH*N][128] (aliases qf; dead after k_ctx)
static const size_t WS_NEED  = 106782720;

// ---------------- helpers ----------------
using bf16x8 = __attribute__((ext_vector_type(8))) short;
using f32x4  = __attribute__((ext_vector_type(4))) float;

__device__ inline float u2f(unsigned int u) {
  union { float f; unsigned int i; } c; c.i = u << 16; return c.f;
}
__device__ inline unsigned short f2u(float x) {
  __hip_bfloat16 h = __float2bfloat16(x);
  unsigned short u; __builtin_memcpy(&u, &h, 2); return u;
}
__device__ inline unsigned int pack2(float lo, float hi) {
  return (unsigned int)f2u(lo) | ((unsigned int)f2u(hi) << 16);
}
__device__ inline void unpack8(uint4 v, float* a) {
  a[0] = u2f(v.x & 0xffffu); a[1] = u2f(v.x >> 16);
  a[2] = u2f(v.y & 0xffffu); a[3] = u2f(v.y >> 16);
  a[4] = u2f(v.z & 0xffffu); a[5] = u2f(v.z >> 16);
  a[6] = u2f(v.w & 0xffffu); a[7] = u2f(v.w >> 16);
}
__device__ inline ushort4 f4tobf(float4 v) {
  ushort4 o;
  o.x = f2u(v.x); o.y = f2u(v.y); o.z = f2u(v.z); o.w = f2u(v.w);
  return o;
}

// ================= K1: MFMA performer features ==================
// out[row][m] = relu(dn * x[row]·proj[m]) + eps  (bf16; m>=266 -> 0)
// 64 rows/block, 272 cols, K=64 in 2 steps of 32. Pattern mirrors k_qk_mfma.
__global__ __launch_bounds__(256) void k_features_mfma(
    const float* __restrict__ q, const float* __restrict__ k,
    const float* __restrict__ proj,
    unsigned short* __restrict__ qf, unsigned short* __restrict__ kf) {
  __shared__ unsigned short at[64][40];    // x tile   [row][k-local], pad-40
  __shared__ unsigned short bt[272][40];   // proj tile[m][k-local]
  const float* x = (blockIdx.y == 0) ? q : k;
  unsigned short* outp = (blockIdx.y == 0) ? qf : kf;
  int tid = threadIdx.x;
  int w = tid >> 6, l = tid & 63;
  int l16 = l & 15, lg = l >> 4;
  int r0 = blockIdx.x * 64;

  f32x4 acc[17] = {};
  for (int kt = 0; kt < 2; ++kt) {
    int k0 = kt * 32;
    __syncthreads();
    // stage A: 64 rows x 32 k (f32 -> bf16)
    #pragma unroll
    for (int p = 0; p < 2; ++p) {
      int idx = tid + p * 256;
      int row = idx >> 3, kq = idx & 7;
      float4 v = *(const float4*)(x + (size_t)(r0 + row) * Dn + k0 + kq * 4);
      *(ushort4*)&at[row][kq * 4] = f4tobf(v);
    }
    // stage B: 272 rows x 32 k
    for (int idx = tid; idx < 2176; idx += 256) {
      int mq = idx >> 3, kq = idx & 7;
      float4 v = make_float4(0.f, 0.f, 0.f, 0.f);
      if (mq < Mn) v = *(const float4*)(proj + (size_t)mq * Dn + k0 + kq * 4);
      *(ushort4*)&bt[mq][kq * 4] = f4tobf(v);
    }
    __syncthreads();
    bf16x8 a = *(const bf16x8*)((const char*)&at[0][0] + (w*16 + l16) * 80 + lg * 16);
    #pragma unroll
    for (int ct = 0; ct < 17; ++ct) {
      bf16x8 b = *(const bf16x8*)((const char*)&bt[0][0] + (ct*16 + l16) * 80 + lg * 16);
      acc[ct] = __builtin_amdgcn_mfma_f32_16x16x32_bf16(a, b, acc[ct], 0, 0, 0);
    }
  }
  // epilogue: relu + eps, bf16 write (row = w*16+lg*4+reg, col = ct*16+l16)
  #pragma unroll
  for (int ct = 0; ct < 17; ++ct)
    #pragma unroll
    for (int reg = 0; reg < 4; ++reg) {
      int row = r0 + w*16 + lg*4 + reg;
      int m = ct*16 + l16;
      float val = 0.f;
      if (m < Mn) val = fmaxf(acc[ct][reg] * DNRM, 0.f) + KEPS;
      outp[(size_t)row * MPn + m] = f2u(val);
    }
}

// ================= K2a: per-chunk kf column sums ==================
__global__ __launch_bounds__(256) void k_ksum(const unsigned short* __restrict__ kf,
                                              float* __restrict__ kpre) {
  int blk = blockIdx.x; int bh = blk >> 4, c = blk & 15;
  int tid = threadIdx.x;
  for (int m = tid; m < MPn; m += 256) {
    const unsigned short* base = kf + ((size_t)bh * Nn + (size_t)c * Cn) * MPn + m;
    float s = 0.f;
    #pragma unroll 8
    for (int j = 0; j < Cn; ++j) s += u2f(base[(size_t)j * MPn]);
    kpre[((size_t)bh * NCn + c) * MPn + m] = s;
  }
}

// ================= K2b: in-place exclusive prefix over chunks ==================
__global__ __launch_bounds__(256) void k_kprefix(float* __restrict__ kpre) {
  int bh = blockIdx.x; int tid = threadIdx.x;
  for (int m = tid; m < MPn; m += 256) {
    float v[NCn];
    #pragma unroll
    for (int c = 0; c < NCn; ++c) v[c] = kpre[((size_t)bh * NCn + c) * MPn + m];
    float acc = 0.f;
    #pragma unroll
    for (int c = 0; c < NCn; ++c) {
      kpre[((size_t)bh * NCn + c) * MPn + m] = acc;
      acc += v[c];
    }
  }
}

// ================= K3: MFMA masked qk + denominator ==================
__global__ __launch_bounds__(256) void k_qk_mfma(
    const unsigned short* __restrict__ qf,
    const unsigned short* __restrict__ kf,
    const float* __restrict__ kpre,
    unsigned short* __restrict__ qkout,
    float* __restrict__ dden) {
  __shared__ unsigned short at[128][40];   // qf tile, pad-40 (conflict-free)
  __shared__ unsigned short ktl[128][40];  // kf tile
  __shared__ float kp[MPn];
  __shared__ float rs_lds[128];
  int blk = blockIdx.x;
  int bh = blk >> 4, c = blk & 15;
  int tid = threadIdx.x;
  int w = tid >> 6, l = tid & 63;
  int l16 = l & 15, lg = l >> 4;
  size_t qbase = ((size_t)bh * Nn + (size_t)c * Cn) * MPn;
  size_t rbase = (size_t)bh * Nn + (size_t)c * Cn;
  for (int m = tid; m < MPn; m += 256) kp[m] = kpre[((size_t)bh * NCn + c) * MPn + m];

  f32x4 acc[2][8] = {};
  for (int kt = 0; kt < 9; ++kt) {
    int mt = kt * 32;
    __syncthreads();
    #pragma unroll
    for (int p = 0; p < 2; ++p) {
      int idx = tid * 8 + p * 2048;
      int r = idx >> 5, kk = idx & 31;
      uint4 va = make_uint4(0u,0u,0u,0u), vk = make_uint4(0u,0u,0u,0u);
      if (mt + kk < MPn) {
        va = *(const uint4*)(qf + qbase + (size_t)r * MPn + mt + kk);
        vk = *(const uint4*)(kf + qbase + (size_t)r * MPn + mt + kk);
      }
      *(uint4*)((char*)&at[0][0] + r * 80 + kk * 2) = va;
      *(uint4*)((char*)&ktl[0][0] + r * 80 + kk * 2) = vk;
    }
    __syncthreads();
    bf16x8 a0 = *(const bf16x8*)((const char*)&at[0][0] + (w*32 + l16) * 80 + lg * 16);
    bf16x8 a1 = *(const bf16x8*)((const char*)&at[0][0] + (w*32 + 16 + l16) * 80 + lg * 16);
    #pragma unroll
    for (int ct = 0; ct < 8; ++ct) {
      bf16x8 b = *(const bf16x8*)((const char*)&ktl[0][0] + (ct*16 + l16) * 80 + lg * 16);
      acc[0][ct] = __builtin_amdgcn_mfma_f32_16x16x32_bf16(a0, b, acc[0][ct], 0, 0, 0);
      acc[1][ct] = __builtin_amdgcn_mfma_f32_16x16x32_bf16(a1, b, acc[1][ct], 0, 0, 0);
    }
  }
  size_t qkbase = (size_t)blk * (Cn * Cn);
  float rs[2][4] = {};
  #pragma unroll
  for (int rt = 0; rt < 2; ++rt)
    #pragma unroll
    for (int ct = 0; ct < 8; ++ct)
      #pragma unroll
      for (int reg = 0; reg < 4; ++reg) {
        int row = w*32 + rt*16 + lg*4 + reg;
        int col = ct*16 + l16;
        float v = (col <= row) ? acc[rt][ct][reg] : 0.f;
        qkout[qkbase + (size_t)row * Cn + col] = f2u(v);
        rs[rt][reg] += v;
      }
  #pragma unroll
  for (int rt = 0; rt < 2; ++rt)
    #pragma unroll
    for (int reg = 0; reg < 4; ++reg) {
      float s = rs[rt][reg];
      s += __shfl_xor(s, 1); s += __shfl_xor(s, 2);
      s += __shfl_xor(s, 4); s += __shfl_xor(s, 8);
      rs[rt][reg] = s;
    }
  if (l16 == 0) {
    #pragma unroll
    for (int rt = 0; rt < 2; ++rt)
      #pragma unroll
      for (int reg = 0; reg < 4; ++reg)
        rs_lds[w*32 + rt*16 + lg*4 + reg] = rs[rt][reg];
  }
  __syncthreads();
  if (tid < 128) {
    float dot = 0.f, qs = 0.f;
    const unsigned short* qrow = qf + qbase + (size_t)tid * MPn;
    for (int m = 0; m < MPn; m += 8) {
      uint4 v = *(const uint4*)(qrow + m);
      float a[8]; unpack8(v, a);
      #pragma unroll
      for (int t = 0; t < 8; ++t) { dot += a[t] * kp[m + t]; qs += a[t]; }
    }
    dden[rbase + tid] = rs_lds[tid] + dot + DEPS * qs;
  }
}

// ================= K4: MFMA per-chunk S^T_c[e][m] = sum_j v[j][e]*kf[j][m] =========
__global__ __launch_bounds__(256) void k_schunk_mfma(
    const unsigned short* __restrict__ kf,
    const float* __restrict__ v3,
    unsigned short* __restrict__ ST) {
  __shared__ unsigned short at[64][40];    // v^T tile  [e-local][j-local]
  __shared__ unsigned short bt[272][40];   // kf^T tile [m][j-local]
  int blk = blockIdx.x, ey = blockIdx.y;
  int bh = blk >> 4, c = blk & 15;
  int e0 = ey * 64;
  int tid = threadIdx.x;
  int w = tid >> 6, l = tid & 63;
  int l16 = l & 15, lg = l >> 4;
  size_t vbase = ((size_t)bh * Nn + (size_t)c * Cn) * E3n + e0;
  size_t kbase = ((size_t)bh * Nn + (size_t)c * Cn) * MPn;

  f32x4 acc[17] = {};
  for (int kt = 0; kt < 4; ++kt) {
    int jt = kt * 32;
    __syncthreads();
    #pragma unroll
    for (int p = 0; p < 2; ++p) {
      int idx = tid + p * 256;
      int j = idx & 31, eq = idx >> 5;
      float4 v = *(const float4*)(v3 + vbase + (size_t)(jt + j) * E3n + eq * 4);
      at[eq*4+0][j] = f2u(v.x); at[eq*4+1][j] = f2u(v.y);
      at[eq*4+2][j] = f2u(v.z); at[eq*4+3][j] = f2u(v.w);
    }
    for (int idx = tid; idx < 1088; idx += 256) {
      int j = idx & 31, mq = idx >> 5;
      uint4 v = *(const uint4*)(kf + kbase + (size_t)(jt + j) * MPn + mq * 8);
      unsigned short tmp[8]; __builtin_memcpy(tmp, &v, 16);
      #pragma unroll
      for (int t = 0; t < 8; ++t) bt[mq*8+t][j] = tmp[t];
    }
    __syncthreads();
    bf16x8 a = *(const bf16x8*)((const char*)&at[0][0] + (w*16 + l16) * 80 + lg * 16);
    #pragma unroll
    for (int ct = 0; ct < 17; ++ct) {
      bf16x8 b = *(const bf16x8*)((const char*)&bt[0][0] + (ct*16 + l16) * 80 + lg * 16);
      acc[ct] = __builtin_amdgcn_mfma_f32_16x16x32_bf16(a, b, acc[ct], 0, 0, 0);
    }
  }
  size_t stbase = (size_t)blk * MPn * E3n + (size_t)e0 * MPn;
  #pragma unroll
  for (int ct = 0; ct < 17; ++ct)
    #pragma unroll
    for (int reg = 0; reg < 4; ++reg) {
      int e_loc = w*16 + lg*4 + reg;
      ST[stbase + (size_t)e_loc * MPn + ct*16 + l16] = f2u(acc[ct][reg]);
    }
}

// ================= K5: in-place exclusive prefix of S^T over chunks (flat) ==========
__global__ __launch_bounds__(256) void k_sprefix(unsigned short* __restrict__ S) {
  int bh = blockIdx.x / 51, sub = blockIdx.x % 51;
  int idx4 = sub * 256 + threadIdx.x;          // 51*256 == MPn*E3n/4 exactly
  size_t off = (size_t)idx4 * 4;
  ushort4 v[NCn];
  #pragma unroll
  for (int c = 0; c < NCn; ++c)
    v[c] = *(const ushort4*)(S + ((size_t)(bh * NCn + c)) * MPn * E3n + off);
  float a0 = 0.f, a1 = 0.f, a2 = 0.f, a3 = 0.f;
  #pragma unroll
  for (int c = 0; c < NCn; ++c) {
    ushort4 o;
    unsigned short* op = (unsigned short*)&o;
    op[0] = f2u(a0); op[1] = f2u(a1); op[2] = f2u(a2); op[3] = f2u(a3);
    *(ushort4*)(S + ((size_t)(bh * NCn + c)) * MPn * E3n + off) = o;
    a0 += u2f(v[c].x); a1 += u2f(v[c].y); a2 += u2f(v[c].z); a3 += u2f(v[c].w);
  }
}

// ================= K6: MFMA ctx = (qf@S_pre + qk@v) / d ==================
__global__ __launch_bounds__(256) void k_ctx_mfma(
    const unsigned short* __restrict__ qf,
    const unsigned short* __restrict__ qkm,
    const unsigned short* __restrict__ ST,   // [blk][192][272]
    const float* __restrict__ v3,
    const float* __restrict__ dden,
    float* __restrict__ ctx) {
  __shared__ unsigned short at[128][40];
  __shared__ unsigned short bt[64][40];
  __shared__ float dd[128];
  int blk = blockIdx.x, ey = blockIdx.y;
  int bh = blk >> 4, c = blk & 15;
  int e0 = ey * 64;
  int tid = threadIdx.x;
  int w = tid >> 6, l = tid & 63;
  int l16 = l & 15, lg = l >> 4;
  size_t qbase = ((size_t)bh * Nn + (size_t)c * Cn) * MPn;
  size_t sbase = (size_t)blk * MPn * E3n + (size_t)e0 * MPn;
  size_t rbase = (size_t)bh * Nn + (size_t)c * Cn;
  if (tid < 128) dd[tid] = dden[rbase + tid];

  f32x4 acc[2][4] = {};
  for (int kt = 0; kt < 9; ++kt) {
    int mt = kt * 32;
    __syncthreads();
    #pragma unroll
    for (int p = 0; p < 2; ++p) {
      int idx = tid * 8 + p * 2048;
      int r = idx >> 5, kk = idx & 31;
      uint4 v = make_uint4(0u,0u,0u,0u);
      if (mt + kk < MPn) v = *(const uint4*)(qf + qbase + (size_t)r * MPn + mt + kk);
      *(uint4*)((char*)&at[0][0] + r * 80 + kk * 2) = v;
    }
    {
      int r = tid >> 2, kk = (tid & 3) * 8;
      uint4 v = make_uint4(0u,0u,0u,0u);
      if (mt + kk < MPn) v = *(const uint4*)(ST + sbase + (size_t)r * MPn + mt + kk);
      *(uint4*)((char*)&bt[0][0] + r * 80 + kk * 2) = v;
    }
    __syncthreads();
    bf16x8 a0 = *(const bf16x8*)((const char*)&at[0][0] + (w*32 + l16) * 80 + lg * 16);
    bf16x8 a1 = *(const bf16x8*)((const char*)&at[0][0] + (w*32 + 16 + l16) * 80 + lg * 16);
    #pragma unroll
    for (int ct = 0; ct < 4; ++ct) {
      bf16x8 b = *(const bf16x8*)((const char*)&bt[0][0] + (ct*16 + l16) * 80 + lg * 16);
      acc[0][ct] = __builtin_amdgcn_mfma_f32_16x16x32_bf16(a0, b, acc[0][ct], 0, 0, 0);
      acc[1][ct] = __builtin_amdgcn_mfma_f32_16x16x32_bf16(a1, b, acc[1][ct], 0, 0, 0);
    }
  }
  size_t kkbase = (size_t)blk * (Cn * Cn);
  size_t vb3 = ((size_t)bh * Nn + (size_t)c * Cn) * E3n + e0;
  for (int kt = 0; kt < 4; ++kt) {
    int jt = kt * 32;
    __syncthreads();
    #pragma unroll
    for (int p = 0; p < 2; ++p) {
      int idx = tid * 8 + p * 2048;
      int r = idx >> 5, kk = idx & 31;
      uint4 v = *(const uint4*)(qkm + kkbase + (size_t)r * Cn + jt + kk);
      *(uint4*)((char*)&at[0][0] + r * 80 + kk * 2) = v;
    }
    #pragma unroll
    for (int p = 0; p < 2; ++p) {
      int idx = tid + p * 256;
      int j = idx & 31, eq = idx >> 5;
      float4 v = *(const float4*)(v3 + vb3 + (size_t)(jt + j) * E3n + eq * 4);
      bt[eq*4+0][j] = f2u(v.x); bt[eq*4+1][j] = f2u(v.y);
      bt[eq*4+2][j] = f2u(v.z); bt[eq*4+3][j] = f2u(v.w);
    }
    __syncthreads();
    bf16x8 a0 = *(const bf16x8*)((const char*)&at[0][0] + (w*32 + l16) * 80 + lg * 16);
    bf16x8 a1 = *(const bf16x8*)((const char*)&at[0][0] + (w*32 + 16 + l16) * 80 + lg * 16);
    #pragma unroll
    for (int ct = 0; ct < 4; ++ct) {
      bf16x8 b = *(const bf16x8*)((const char*)&bt[0][0] + (ct*16 + l16) * 80 + lg * 16);
      acc[0][ct] = __builtin_amdgcn_mfma_f32_16x16x32_bf16(a0, b, acc[0][ct], 0, 0, 0);
      acc[1][ct] = __builtin_amdgcn_mfma_f32_16x16x32_bf16(a1, b, acc[1][ct], 0, 0, 0);
    }
  }
  #pragma unroll
  for (int rt = 0; rt < 2; ++rt)
    #pragma unroll
    for (int ct = 0; ct < 4; ++ct)
      #pragma unroll
      for (int reg = 0; reg < 4; ++reg) {
        int row = w*32 + rt*16 + lg*4 + reg;
        float inv = 1.f / dd[row];
        ctx[(rbase + row) * (size_t)E3n + e0 + ct*16 + l16] = acc[rt][ct][reg] * inv;
      }
}

// ================= K7a: h = GELU(LN(ctx @ enc_w + enc_b)) -> bf16 ==================
__global__ __launch_bounds__(256) void k_enc(const float* __restrict__ ctx,
    const float* __restrict__ enc_w, const float* __restrict__ enc_b,
    const float* __restrict__ ln_g, const float* __restrict__ ln_b,
    unsigned short* __restrict__ h) {
  __shared__ float ct[64][200];
  int tid = threadIdx.x;
  int r0 = blockIdx.x * 64;
  #pragma unroll
  for (int it = 0; it < 12; ++it) {
    int idx = tid * 4 + it * 1024;
    int row = idx / 192, e = idx % 192;
    float4 v = *(const float4*)(ctx + (size_t)(r0 + row) * E3n + e);
    *(float4*)&ct[row][e] = v;
  }
  __syncthreads();
  int tx = tid & 15, ty = tid >> 4;
  float acc[4][8] = {};
  #pragma unroll 2
  for (int e = 0; e < E3n; ++e) {
    float4 w0 = *(const float4*)(enc_w + (size_t)e * DHn + tx * 8);
    float4 w1 = *(const float4*)(enc_w + (size_t)e * DHn + tx * 8 + 4);
    float w[8] = {w0.x, w0.y, w0.z, w0.w, w1.x, w1.y, w1.z, w1.w};
    #pragma unroll
    for (int i = 0; i < 4; ++i) {
      float a = ct[ty + 16 * i][e];
      #pragma unroll
      for (int j = 0; j < 8; ++j) acc[i][j] += a * w[j];
    }
  }
  float4 b0 = *(const float4*)(enc_b + tx * 8);
  float4 b1 = *(const float4*)(enc_b + tx * 8 + 4);
  float bb[8] = {b0.x, b0.y, b0.z, b0.w, b1.x, b1.y, b1.z, b1.w};
  float4 g0 = *(const float4*)(ln_g + tx * 8);
  float4 g1 = *(const float4*)(ln_g + tx * 8 + 4);
  float gg[8] = {g0.x, g0.y, g0.z, g0.w, g1.x, g1.y, g1.z, g1.w};
  float4 l0 = *(const float4*)(ln_b + tx * 8);
  float4 l1 = *(const float4*)(ln_b + tx * 8 + 4);
  float ll[8] = {l0.x, l0.y, l0.z, l0.w, l1.x, l1.y, l1.z, l1.w};
  #pragma unroll
  for (int i = 0; i < 4; ++i) {
    float s = 0.f, s2 = 0.f;
    #pragma unroll
    for (int j = 0; j < 8; ++j) {
      acc[i][j] += bb[j];
      s += acc[i][j]; s2 += acc[i][j] * acc[i][j];
    }
    #pragma unroll
    for (int m = 1; m < 16; m <<= 1) {
      s += __shfl_xor(s, m);
      s2 += __shfl_xor(s2, m);
    }
    float mu = s * (1.f / 128.f);
    float var = s2 * (1.f / 128.f) - mu * mu;
    float rs = rsqrtf(var + LNEPS);
    uint4 o;
    unsigned int* op = (unsigned int*)&o;
    #pragma unroll
    for (int j2 = 0; j2 < 4; ++j2) {
      float v0 = (acc[i][2 * j2] - mu) * rs * gg[2 * j2] + ll[2 * j2];
      float v1 = (acc[i][2 * j2 + 1] - mu) * rs * gg[2 * j2 + 1] + ll[2 * j2 + 1];
      v0 = 0.5f * v0 * (1.f + erff(v0 * 0.70710678118654752f));
      v1 = 0.5f * v1 * (1.f + erff(v1 * 0.70710678118654752f));
      op[j2] = pack2(v0, v1);
    }
    *(uint4*)(h + (size_t)(r0 + ty + 16 * i) * DHn + tx * 8) = o;
  }
}

// ================= K7b: probs = softmax(h @ dec_w + dec_b) ==================
__global__ __launch_bounds__(256) void k_dec(const unsigned short* __restrict__ h,
    const float* __restrict__ dec_w, const float* __restrict__ dec_b,
    float* __restrict__ probs) {
  __shared__ float ht[64][136];
  int tid = threadIdx.x;
  int r0 = blockIdx.x * 64;
  #pragma unroll
  for (int it = 0; it < 4; ++it) {
    int idx = tid * 8 + it * 2048;
    int row = idx >> 7, c = idx & 127;
    uint4 u = *(const uint4*)(h + (size_t)(r0 + row) * DHn + c);
    float a[8]; unpack8(u, a);
    *(float4*)&ht[row][c] = make_float4(a[0], a[1], a[2], a[3]);
    *(float4*)&ht[row][c + 4] = make_float4(a[4], a[5], a[6], a[7]);
  }
  __syncthreads();
  int tx = tid & 15, ty = tid >> 4;
  float acc[4][8] = {};
  #pragma unroll 2
  for (int c = 0; c < DHn; ++c) {
    float4 w0 = *(const float4*)(dec_w + (size_t)c * Tn + tx * 8);
    float4 w1 = *(const float4*)(dec_w + (size_t)c * Tn + tx * 8 + 4);
    float w[8] = {w0.x, w0.y, w0.z, w0.w, w1.x, w1.y, w1.z, w1.w};
    #pragma unroll
    for (int i = 0; i < 4; ++i) {
      float a = ht[ty + 16 * i][c];
      #pragma unroll
      for (int j = 0; j < 8; ++j) acc[i][j] += a * w[j];
    }
  }
  float4 b0 = *(const float4*)(dec_b + tx * 8);
  float4 b1 = *(const float4*)(dec_b + tx * 8 + 4);
  float bb[8] = {b0.x, b0.y, b0.z, b0.w, b1.x, b1.y, b1.z, b1.w};
  #pragma unroll
  for (int i = 0; i < 4; ++i) {
    float m = -1e30f;
    #pragma unroll
    for (int j = 0; j < 8; ++j) {
      acc[i][j] += bb[j];
      m = fmaxf(m, acc[i][j]);
    }
    #pragma unroll
    for (int mm = 1; mm < 16; mm <<= 1) m = fmaxf(m, __shfl_xor(m, mm));
    float s = 0.f;
    #pragma unroll
    for (int j = 0; j < 8; ++j) { acc[i][j] = expf(acc[i][j] - m); s += acc[i][j]; }
    #pragma unroll
    for (int mm = 1; mm < 16; mm <<= 1) s += __shfl_xor(s, mm);
    float inv = 1.f / s;
    float4 oa = {acc[i][0] * inv, acc[i][1] * inv, acc[i][2] * inv, acc[i][3] * inv};
    float4 ob = {acc[i][4] * inv, acc[i][5] * inv, acc[i][6] * inv, acc[i][7] * inv};
    size_t base = (size_t)(r0 + ty + 16 * i) * Tn + tx * 8;
    *(float4*)(probs + base) = oa;
    *(float4*)(probs + base + 4) = ob;
  }
}

// ================= launch ==================
extern "C" void kernel_launch(void* const* d_in, const int* in_sizes, int n_in,
                              void* d_out, int out_size, void* d_ws, size_t ws_size,
                              hipStream_t stream) {
  const float* q     = (const float*)d_in[0];
  const float* k     = (const float*)d_in[1];
  const float* v3    = (const float*)d_in[2];
  const float* proj  = (const float*)d_in[3];
  const float* enc_w = (const float*)d_in[4];
  const float* enc_b = (const float*)d_in[5];
  const float* ln_g  = (const float*)d_in[6];
  const float* ln_b  = (const float*)d_in[7];
  const float* dec_w = (const float*)d_in[8];
  const float* dec_b = (const float*)d_in[9];
  float* out = (float*)d_out;
  char* ws = (char*)d_ws;
  if (ws_size < WS_NEED) return;

  unsigned short* qf   = (unsigned short*)(ws + OFF_QF);
  unsigned short* kf   = (unsigned short*)(ws + OFF_KF);
  unsigned short* qk   = (unsigned short*)(ws + OFF_QK);
  float*          dden = (float*)(ws + OFF_D);
  float*          kpre = (float*)(ws + OFF_KPRE);
  unsigned short* ST   = (unsigned short*)(ws + OFF_S);
  unsigned short* hbuf = (unsigned short*)(ws + OFF_H);   // aliases qf (dead after k_ctx)
  float* ctx   = out;
  float* probs = out + (size_t)BHn * Nn * E3n;

  k_features_mfma<<<dim3(BHn * Nn / 64, 2), 256, 0, stream>>>(q, k, proj, qf, kf);
  k_ksum      <<<dim3(BHn * NCn),       256, 0, stream>>>(kf, kpre);
  k_kprefix   <<<dim3(BHn),             256, 0, stream>>>(kpre);
  k_qk_mfma   <<<dim3(BHn * NCn),       256, 0, stream>>>(qf, kf, kpre, qk, dden);
  k_schunk_mfma<<<dim3(BHn * NCn, 3),   256, 0, stream>>>(kf, v3, ST);
  k_sprefix   <<<dim3(BHn * 51),        256, 0, stream>>>(ST);
  k_ctx_mfma  <<<dim3(BHn * NCn, 3),    256, 0, stream>>>(qf, qk, ST, v3, dden, ctx);
  k_enc       <<<dim3(BHn * Nn / 64),   256, 0, stream>>>(ctx, enc_w, enc_b, ln_g, ln_b, hbuf);
  k_dec       <<<dim3(BHn * Nn / 64),   256, 0, stream>>>(hbuf, dec_w, dec_b, probs);
}

// Round 6
// 168.697 us; speedup vs baseline: 3.2708x; 1.2868x over previous
//
#include <hip/hip_runtime.h>
#include <hip/hip_bf16.h>
#include <math.h>

// ---------------- problem constants ----------------
constexpr int Bn = 2, Hn = 12, BHn = 24;
constexpr int Nn = 2048, Dn = 64;
constexpr int Mn = 266, MPn = 272;          // M padded to 272 (zero-filled)
constexpr int E3n = 192, DHn = 128, Tn = 128;
constexpr int Cn = 128, NCn = 16;           // chunking

#define DNRM 0.35355339059327373f   // 64^-0.25
#define KEPS 1e-3f
#define DEPS 1e-6f
#define LNEPS 1e-5f

// ---------------- ws layout (bytes) ----------------
static const size_t OFF_QF   = 0;            // bf16 [BH][N][MP]   26,738,688
static const size_t OFF_KF   = 26738688;     // bf16 [BH][N][MP]
static const size_t OFF_QK   = 53477376;     // bf16 [BH][NC][C][C] 12,582,912
static const size_t OFF_D    = 66060288;     // f32  [BH][N]          196,608
static const size_t OFF_KPRE = 66256896;     // f32  [BH][NC][MP]     417,792
static const size_t OFF_S    = 66674688;     // bf16 [BH][NC][192][272] (S^T) 40,108,032
static const size_t OFF_WT   = OFF_KF;       // bf16 ewt[128][192]+dwt[128][128] (aliases kf; dead after k_schunk)
static const size_t WS_NEED  = 106782720;

// ---------------- helpers ----------------
using bf16x8 = __attribute__((ext_vector_type(8))) short;
using f32x4  = __attribute__((ext_vector_type(4))) float;

__device__ inline float u2f(unsigned int u) {
  union { float f; unsigned int i; } c; c.i = u << 16; return c.f;
}
__device__ inline unsigned short f2u(float x) {
  __hip_bfloat16 h = __float2bfloat16(x);
  unsigned short u; __builtin_memcpy(&u, &h, 2); return u;
}
__device__ inline void unpack8(uint4 v, float* a) {
  a[0] = u2f(v.x & 0xffffu); a[1] = u2f(v.x >> 16);
  a[2] = u2f(v.y & 0xffffu); a[3] = u2f(v.y >> 16);
  a[4] = u2f(v.z & 0xffffu); a[5] = u2f(v.z >> 16);
  a[6] = u2f(v.w & 0xffffu); a[7] = u2f(v.w >> 16);
}
__device__ inline ushort4 f4tobf(float4 v) {
  ushort4 o;
  o.x = f2u(v.x); o.y = f2u(v.y); o.z = f2u(v.z); o.w = f2u(v.w);
  return o;
}

// ================= K1: MFMA performer features ==================
__global__ __launch_bounds__(256) void k_features_mfma(
    const float* __restrict__ q, const float* __restrict__ k,
    const float* __restrict__ proj,
    unsigned short* __restrict__ qf, unsigned short* __restrict__ kf) {
  __shared__ unsigned short at[64][40];    // x tile   [row][k-local], pad-40
  __shared__ unsigned short bt[272][40];   // proj tile[m][k-local]
  const float* x = (blockIdx.y == 0) ? q : k;
  unsigned short* outp = (blockIdx.y == 0) ? qf : kf;
  int tid = threadIdx.x;
  int w = tid >> 6, l = tid & 63;
  int l16 = l & 15, lg = l >> 4;
  int r0 = blockIdx.x * 64;

  f32x4 acc[17] = {};
  for (int kt = 0; kt < 2; ++kt) {
    int k0 = kt * 32;
    __syncthreads();
    #pragma unroll
    for (int p = 0; p < 2; ++p) {
      int idx = tid + p * 256;
      int row = idx >> 3, kq = idx & 7;
      float4 v = *(const float4*)(x + (size_t)(r0 + row) * Dn + k0 + kq * 4);
      *(ushort4*)&at[row][kq * 4] = f4tobf(v);
    }
    for (int idx = tid; idx < 2176; idx += 256) {
      int mq = idx >> 3, kq = idx & 7;
      float4 v = make_float4(0.f, 0.f, 0.f, 0.f);
      if (mq < Mn) v = *(const float4*)(proj + (size_t)mq * Dn + k0 + kq * 4);
      *(ushort4*)&bt[mq][kq * 4] = f4tobf(v);
    }
    __syncthreads();
    bf16x8 a = *(const bf16x8*)((const char*)&at[0][0] + (w*16 + l16) * 80 + lg * 16);
    #pragma unroll
    for (int ct = 0; ct < 17; ++ct) {
      bf16x8 b = *(const bf16x8*)((const char*)&bt[0][0] + (ct*16 + l16) * 80 + lg * 16);
      acc[ct] = __builtin_amdgcn_mfma_f32_16x16x32_bf16(a, b, acc[ct], 0, 0, 0);
    }
  }
  #pragma unroll
  for (int ct = 0; ct < 17; ++ct)
    #pragma unroll
    for (int reg = 0; reg < 4; ++reg) {
      int row = r0 + w*16 + lg*4 + reg;
      int m = ct*16 + l16;
      float val = 0.f;
      if (m < Mn) val = fmaxf(acc[ct][reg] * DNRM, 0.f) + KEPS;
      outp[(size_t)row * MPn + m] = f2u(val);
    }
}

// ================= K2a: per-chunk kf column sums ==================
__global__ __launch_bounds__(256) void k_ksum(const unsigned short* __restrict__ kf,
                                              float* __restrict__ kpre) {
  int blk = blockIdx.x; int bh = blk >> 4, c = blk & 15;
  int tid = threadIdx.x;
  for (int m = tid; m < MPn; m += 256) {
    const unsigned short* base = kf + ((size_t)bh * Nn + (size_t)c * Cn) * MPn + m;
    float s = 0.f;
    #pragma unroll 8
    for (int j = 0; j < Cn; ++j) s += u2f(base[(size_t)j * MPn]);
    kpre[((size_t)bh * NCn + c) * MPn + m] = s;
  }
}

// ================= K2b: in-place exclusive prefix over chunks ==================
__global__ __launch_bounds__(256) void k_kprefix(float* __restrict__ kpre) {
  int bh = blockIdx.x; int tid = threadIdx.x;
  for (int m = tid; m < MPn; m += 256) {
    float v[NCn];
    #pragma unroll
    for (int c = 0; c < NCn; ++c) v[c] = kpre[((size_t)bh * NCn + c) * MPn + m];
    float acc = 0.f;
    #pragma unroll
    for (int c = 0; c < NCn; ++c) {
      kpre[((size_t)bh * NCn + c) * MPn + m] = acc;
      acc += v[c];
    }
  }
}

// ================= K3: MFMA masked qk + denominator ==================
__global__ __launch_bounds__(256) void k_qk_mfma(
    const unsigned short* __restrict__ qf,
    const unsigned short* __restrict__ kf,
    const float* __restrict__ kpre,
    unsigned short* __restrict__ qkout,
    float* __restrict__ dden) {
  __shared__ unsigned short at[128][40];
  __shared__ unsigned short ktl[128][40];
  __shared__ float kp[MPn];
  __shared__ float rs_lds[128];
  int blk = blockIdx.x;
  int bh = blk >> 4, c = blk & 15;
  int tid = threadIdx.x;
  int w = tid >> 6, l = tid & 63;
  int l16 = l & 15, lg = l >> 4;
  size_t qbase = ((size_t)bh * Nn + (size_t)c * Cn) * MPn;
  size_t rbase = (size_t)bh * Nn + (size_t)c * Cn;
  for (int m = tid; m < MPn; m += 256) kp[m] = kpre[((size_t)bh * NCn + c) * MPn + m];

  f32x4 acc[2][8] = {};
  for (int kt = 0; kt < 9; ++kt) {
    int mt = kt * 32;
    __syncthreads();
    #pragma unroll
    for (int p = 0; p < 2; ++p) {
      int idx = tid * 8 + p * 2048;
      int r = idx >> 5, kk = idx & 31;
      uint4 va = make_uint4(0u,0u,0u,0u), vk = make_uint4(0u,0u,0u,0u);
      if (mt + kk < MPn) {
        va = *(const uint4*)(qf + qbase + (size_t)r * MPn + mt + kk);
        vk = *(const uint4*)(kf + qbase + (size_t)r * MPn + mt + kk);
      }
      *(uint4*)((char*)&at[0][0] + r * 80 + kk * 2) = va;
      *(uint4*)((char*)&ktl[0][0] + r * 80 + kk * 2) = vk;
    }
    __syncthreads();
    bf16x8 a0 = *(const bf16x8*)((const char*)&at[0][0] + (w*32 + l16) * 80 + lg * 16);
    bf16x8 a1 = *(const bf16x8*)((const char*)&at[0][0] + (w*32 + 16 + l16) * 80 + lg * 16);
    #pragma unroll
    for (int ct = 0; ct < 8; ++ct) {
      bf16x8 b = *(const bf16x8*)((const char*)&ktl[0][0] + (ct*16 + l16) * 80 + lg * 16);
      acc[0][ct] = __builtin_amdgcn_mfma_f32_16x16x32_bf16(a0, b, acc[0][ct], 0, 0, 0);
      acc[1][ct] = __builtin_amdgcn_mfma_f32_16x16x32_bf16(a1, b, acc[1][ct], 0, 0, 0);
    }
  }
  size_t qkbase = (size_t)blk * (Cn * Cn);
  float rs[2][4] = {};
  #pragma unroll
  for (int rt = 0; rt < 2; ++rt)
    #pragma unroll
    for (int ct = 0; ct < 8; ++ct)
      #pragma unroll
      for (int reg = 0; reg < 4; ++reg) {
        int row = w*32 + rt*16 + lg*4 + reg;
        int col = ct*16 + l16;
        float v = (col <= row) ? acc[rt][ct][reg] : 0.f;
        qkout[qkbase + (size_t)row * Cn + col] = f2u(v);
        rs[rt][reg] += v;
      }
  #pragma unroll
  for (int rt = 0; rt < 2; ++rt)
    #pragma unroll
    for (int reg = 0; reg < 4; ++reg) {
      float s = rs[rt][reg];
      s += __shfl_xor(s, 1); s += __shfl_xor(s, 2);
      s += __shfl_xor(s, 4); s += __shfl_xor(s, 8);
      rs[rt][reg] = s;
    }
  if (l16 == 0) {
    #pragma unroll
    for (int rt = 0; rt < 2; ++rt)
      #pragma unroll
      for (int reg = 0; reg < 4; ++reg)
        rs_lds[w*32 + rt*16 + lg*4 + reg] = rs[rt][reg];
  }
  __syncthreads();
  if (tid < 128) {
    float dot = 0.f, qs = 0.f;
    const unsigned short* qrow = qf + qbase + (size_t)tid * MPn;
    for (int m = 0; m < MPn; m += 8) {
      uint4 v = *(const uint4*)(qrow + m);
      float a[8]; unpack8(v, a);
      #pragma unroll
      for (int t = 0; t < 8; ++t) { dot += a[t] * kp[m + t]; qs += a[t]; }
    }
    dden[rbase + tid] = rs_lds[tid] + dot + DEPS * qs;
  }
}

// ================= K4: MFMA per-chunk S^T_c[e][m] = sum_j v[j][e]*kf[j][m] =========
__global__ __launch_bounds__(256) void k_schunk_mfma(
    const unsigned short* __restrict__ kf,
    const float* __restrict__ v3,
    unsigned short* __restrict__ ST) {
  __shared__ unsigned short at[64][40];
  __shared__ unsigned short bt[272][40];
  int blk = blockIdx.x, ey = blockIdx.y;
  int bh = blk >> 4, c = blk & 15;
  int e0 = ey * 64;
  int tid = threadIdx.x;
  int w = tid >> 6, l = tid & 63;
  int l16 = l & 15, lg = l >> 4;
  size_t vbase = ((size_t)bh * Nn + (size_t)c * Cn) * E3n + e0;
  size_t kbase = ((size_t)bh * Nn + (size_t)c * Cn) * MPn;

  f32x4 acc[17] = {};
  for (int kt = 0; kt < 4; ++kt) {
    int jt = kt * 32;
    __syncthreads();
    #pragma unroll
    for (int p = 0; p < 2; ++p) {
      int idx = tid + p * 256;
      int j = idx & 31, eq = idx >> 5;
      float4 v = *(const float4*)(v3 + vbase + (size_t)(jt + j) * E3n + eq * 4);
      at[eq*4+0][j] = f2u(v.x); at[eq*4+1][j] = f2u(v.y);
      at[eq*4+2][j] = f2u(v.z); at[eq*4+3][j] = f2u(v.w);
    }
    for (int idx = tid; idx < 1088; idx += 256) {
      int j = idx & 31, mq = idx >> 5;
      uint4 v = *(const uint4*)(kf + kbase + (size_t)(jt + j) * MPn + mq * 8);
      unsigned short tmp[8]; __builtin_memcpy(tmp, &v, 16);
      #pragma unroll
      for (int t = 0; t < 8; ++t) bt[mq*8+t][j] = tmp[t];
    }
    __syncthreads();
    bf16x8 a = *(const bf16x8*)((const char*)&at[0][0] + (w*16 + l16) * 80 + lg * 16);
    #pragma unroll
    for (int ct = 0; ct < 17; ++ct) {
      bf16x8 b = *(const bf16x8*)((const char*)&bt[0][0] + (ct*16 + l16) * 80 + lg * 16);
      acc[ct] = __builtin_amdgcn_mfma_f32_16x16x32_bf16(a, b, acc[ct], 0, 0, 0);
    }
  }
  size_t stbase = (size_t)blk * MPn * E3n + (size_t)e0 * MPn;
  #pragma unroll
  for (int ct = 0; ct < 17; ++ct)
    #pragma unroll
    for (int reg = 0; reg < 4; ++reg) {
      int e_loc = w*16 + lg*4 + reg;
      ST[stbase + (size_t)e_loc * MPn + ct*16 + l16] = f2u(acc[ct][reg]);
    }
}

// ================= K4b: transpose+bf16 weights: ewt[n][e], dwt[t][c] ==============
__global__ __launch_bounds__(256) void k_wt(const float* __restrict__ enc_w,
    const float* __restrict__ dec_w, unsigned short* __restrict__ ewt,
    unsigned short* __restrict__ dwt) {
  int i = blockIdx.x * 256 + threadIdx.x;
  if (i < 128 * 192) {
    int n = i / 192, e = i - n * 192;
    ewt[i] = f2u(enc_w[(size_t)e * DHn + n]);
  } else {
    int j = i - 128 * 192;
    int t = j >> 7, c = j & 127;
    dwt[(size_t)t * DHn + c] = f2u(dec_w[(size_t)c * Tn + t]);
  }
}

// ================= K5: in-place exclusive prefix of S^T over chunks (flat) ==========
__global__ __launch_bounds__(256) void k_sprefix(unsigned short* __restrict__ S) {
  int bh = blockIdx.x / 51, sub = blockIdx.x % 51;
  int idx4 = sub * 256 + threadIdx.x;          // 51*256 == MPn*E3n/4 exactly
  size_t off = (size_t)idx4 * 4;
  ushort4 v[NCn];
  #pragma unroll
  for (int c = 0; c < NCn; ++c)
    v[c] = *(const ushort4*)(S + ((size_t)(bh * NCn + c)) * MPn * E3n + off);
  float a0 = 0.f, a1 = 0.f, a2 = 0.f, a3 = 0.f;
  #pragma unroll
  for (int c = 0; c < NCn; ++c) {
    ushort4 o;
    unsigned short* op = (unsigned short*)&o;
    op[0] = f2u(a0); op[1] = f2u(a1); op[2] = f2u(a2); op[3] = f2u(a3);
    *(ushort4*)(S + ((size_t)(bh * NCn + c)) * MPn * E3n + off) = o;
    a0 += u2f(v[c].x); a1 += u2f(v[c].y); a2 += u2f(v[c].z); a3 += u2f(v[c].w);
  }
}

// ================= K6: MFMA ctx = (qf@S_pre + qk@v) / d ==================
__global__ __launch_bounds__(256) void k_ctx_mfma(
    const unsigned short* __restrict__ qf,
    const unsigned short* __restrict__ qkm,
    const unsigned short* __restrict__ ST,
    const float* __restrict__ v3,
    const float* __restrict__ dden,
    float* __restrict__ ctx) {
  __shared__ unsigned short at[128][40];
  __shared__ unsigned short bt[64][40];
  __shared__ float dd[128];
  int blk = blockIdx.x, ey = blockIdx.y;
  int bh = blk >> 4, c = blk & 15;
  int e0 = ey * 64;
  int tid = threadIdx.x;
  int w = tid >> 6, l = tid & 63;
  int l16 = l & 15, lg = l >> 4;
  size_t qbase = ((size_t)bh * Nn + (size_t)c * Cn) * MPn;
  size_t sbase = (size_t)blk * MPn * E3n + (size_t)e0 * MPn;
  size_t rbase = (size_t)bh * Nn + (size_t)c * Cn;
  if (tid < 128) dd[tid] = dden[rbase + tid];

  f32x4 acc[2][4] = {};
  for (int kt = 0; kt < 9; ++kt) {
    int mt = kt * 32;
    __syncthreads();
    #pragma unroll
    for (int p = 0; p < 2; ++p) {
      int idx = tid * 8 + p * 2048;
      int r = idx >> 5, kk = idx & 31;
      uint4 v = make_uint4(0u,0u,0u,0u);
      if (mt + kk < MPn) v = *(const uint4*)(qf + qbase + (size_t)r * MPn + mt + kk);
      *(uint4*)((char*)&at[0][0] + r * 80 + kk * 2) = v;
    }
    {
      int r = tid >> 2, kk = (tid & 3) * 8;
      uint4 v = make_uint4(0u,0u,0u,0u);
      if (mt + kk < MPn) v = *(const uint4*)(ST + sbase + (size_t)r * MPn + mt + kk);
      *(uint4*)((char*)&bt[0][0] + r * 80 + kk * 2) = v;
    }
    __syncthreads();
    bf16x8 a0 = *(const bf16x8*)((const char*)&at[0][0] + (w*32 + l16) * 80 + lg * 16);
    bf16x8 a1 = *(const bf16x8*)((const char*)&at[0][0] + (w*32 + 16 + l16) * 80 + lg * 16);
    #pragma unroll
    for (int ct = 0; ct < 4; ++ct) {
      bf16x8 b = *(const bf16x8*)((const char*)&bt[0][0] + (ct*16 + l16) * 80 + lg * 16);
      acc[0][ct] = __builtin_amdgcn_mfma_f32_16x16x32_bf16(a0, b, acc[0][ct], 0, 0, 0);
      acc[1][ct] = __builtin_amdgcn_mfma_f32_16x16x32_bf16(a1, b, acc[1][ct], 0, 0, 0);
    }
  }
  size_t kkbase = (size_t)blk * (Cn * Cn);
  size_t vb3 = ((size_t)bh * Nn + (size_t)c * Cn) * E3n + e0;
  for (int kt = 0; kt < 4; ++kt) {
    int jt = kt * 32;
    __syncthreads();
    #pragma unroll
    for (int p = 0; p < 2; ++p) {
      int idx = tid * 8 + p * 2048;
      int r = idx >> 5, kk = idx & 31;
      uint4 v = *(const uint4*)(qkm + kkbase + (size_t)r * Cn + jt + kk);
      *(uint4*)((char*)&at[0][0] + r * 80 + kk * 2) = v;
    }
    #pragma unroll
    for (int p = 0; p < 2; ++p) {
      int idx = tid + p * 256;
      int j = idx & 31, eq = idx >> 5;
      float4 v = *(const float4*)(v3 + vb3 + (size_t)(jt + j) * E3n + eq * 4);
      bt[eq*4+0][j] = f2u(v.x); bt[eq*4+1][j] = f2u(v.y);
      bt[eq*4+2][j] = f2u(v.z); bt[eq*4+3][j] = f2u(v.w);
    }
    __syncthreads();
    bf16x8 a0 = *(const bf16x8*)((const char*)&at[0][0] + (w*32 + l16) * 80 + lg * 16);
    bf16x8 a1 = *(const bf16x8*)((const char*)&at[0][0] + (w*32 + 16 + l16) * 80 + lg * 16);
    #pragma unroll
    for (int ct = 0; ct < 4; ++ct) {
      bf16x8 b = *(const bf16x8*)((const char*)&bt[0][0] + (ct*16 + l16) * 80 + lg * 16);
      acc[0][ct] = __builtin_amdgcn_mfma_f32_16x16x32_bf16(a0, b, acc[0][ct], 0, 0, 0);
      acc[1][ct] = __builtin_amdgcn_mfma_f32_16x16x32_bf16(a1, b, acc[1][ct], 0, 0, 0);
    }
  }
  #pragma unroll
  for (int rt = 0; rt < 2; ++rt)
    #pragma unroll
    for (int ct = 0; ct < 4; ++ct)
      #pragma unroll
      for (int reg = 0; reg < 4; ++reg) {
        int row = w*32 + rt*16 + lg*4 + reg;
        float inv = 1.f / dd[row];
        ctx[(rbase + row) * (size_t)E3n + e0 + ct*16 + l16] = acc[rt][ct][reg] * inv;
      }
}

// ================= K7: fused predictor: MFMA enc -> LN+GELU -> MFMA dec -> softmax ==
// 128 rows/block; ewt[n][k], dwt[t][k] pre-transposed bf16.
__global__ __launch_bounds__(256) void k_pred_fused(
    const float* __restrict__ ctx,
    const unsigned short* __restrict__ ewt,
    const unsigned short* __restrict__ dwt,
    const float* __restrict__ enc_b, const float* __restrict__ ln_g,
    const float* __restrict__ ln_b, const float* __restrict__ dec_b,
    float* __restrict__ probs) {
  __shared__ unsigned short at[128][40];   // ctx tile (bf16), pad-40
  __shared__ unsigned short bt[128][40];   // weight tile, pad-40
  __shared__ unsigned short ht[128][200];  // h (bf16); 400B row stride: 16B-aligned, 2-way banks
  int tid = threadIdx.x;
  int w = tid >> 6, l = tid & 63;
  int l16 = l & 15, lg = l >> 4;
  size_t r0 = (size_t)blockIdx.x * 128;

  float ebv[8], ggv[8], llv[8], dbv[8];
  #pragma unroll
  for (int ct = 0; ct < 8; ++ct) {
    ebv[ct] = enc_b[ct*16 + l16];
    ggv[ct] = ln_g[ct*16 + l16];
    llv[ct] = ln_b[ct*16 + l16];
    dbv[ct] = dec_b[ct*16 + l16];
  }

  // phase 1: h = ctx @ enc_w  (K=192, 6 steps)
  f32x4 acc1[2][8] = {};
  for (int kt = 0; kt < 6; ++kt) {
    int k0 = kt * 32;
    __syncthreads();
    #pragma unroll
    for (int p = 0; p < 4; ++p) {
      int idx = tid + p * 256;
      int row = idx >> 3, kq = idx & 7;
      float4 v = *(const float4*)(ctx + (r0 + row) * E3n + k0 + kq * 4);
      *(ushort4*)&at[row][kq * 4] = f4tobf(v);
    }
    #pragma unroll
    for (int p = 0; p < 2; ++p) {
      int idx = tid + p * 256;
      int n = idx >> 2, kq = idx & 3;
      *(uint4*)&bt[n][kq * 8] = *(const uint4*)(ewt + (size_t)n * E3n + k0 + kq * 8);
    }
    __syncthreads();
    bf16x8 a0 = *(const bf16x8*)((const char*)&at[0][0] + (w*32 + l16) * 80 + lg * 16);
    bf16x8 a1 = *(const bf16x8*)((const char*)&at[0][0] + (w*32 + 16 + l16) * 80 + lg * 16);
    #pragma unroll
    for (int ct = 0; ct < 8; ++ct) {
      bf16x8 b = *(const bf16x8*)((const char*)&bt[0][0] + (ct*16 + l16) * 80 + lg * 16);
      acc1[0][ct] = __builtin_amdgcn_mfma_f32_16x16x32_bf16(a0, b, acc1[0][ct], 0, 0, 0);
      acc1[1][ct] = __builtin_amdgcn_mfma_f32_16x16x32_bf16(a1, b, acc1[1][ct], 0, 0, 0);
    }
  }
  // LN + GELU in registers (row = 16-lane shfl group), write h bf16 to ht
  #pragma unroll
  for (int rt = 0; rt < 2; ++rt) {
    #pragma unroll
    for (int reg = 0; reg < 4; ++reg) {
      float hv[8];
      float s = 0.f, s2 = 0.f;
      #pragma unroll
      for (int ct = 0; ct < 8; ++ct) {
        float v = acc1[rt][ct][reg] + ebv[ct];
        hv[ct] = v; s += v; s2 += v * v;
      }
      #pragma unroll
      for (int m = 1; m < 16; m <<= 1) { s += __shfl_xor(s, m); s2 += __shfl_xor(s2, m); }
      float mu = s * (1.f / 128.f);
      float var = s2 * (1.f / 128.f) - mu * mu;
      float rsq = rsqrtf(var + LNEPS);
      int row = w*32 + rt*16 + lg*4 + reg;
      #pragma unroll
      for (int ct = 0; ct < 8; ++ct) {
        float v = (hv[ct] - mu) * rsq * ggv[ct] + llv[ct];
        v = 0.5f * v * (1.f + erff(v * 0.70710678118654752f));
        ht[row][ct*16 + l16] = f2u(v);
      }
    }
  }
  // phase 2: scores = h @ dec_w (K=128, 4 steps); A from ht (rows are wave-private)
  f32x4 acc2[2][8] = {};
  for (int kt = 0; kt < 4; ++kt) {
    int c0 = kt * 32;
    __syncthreads();
    #pragma unroll
    for (int p = 0; p < 2; ++p) {
      int idx = tid + p * 256;
      int t = idx >> 2, kq = idx & 3;
      *(uint4*)&bt[t][kq * 8] = *(const uint4*)(dwt + (size_t)t * DHn + c0 + kq * 8);
    }
    __syncthreads();
    bf16x8 a0 = *(const bf16x8*)&ht[w*32 + l16][c0 + lg*8];
    bf16x8 a1 = *(const bf16x8*)&ht[w*32 + 16 + l16][c0 + lg*8];
    #pragma unroll
    for (int ct = 0; ct < 8; ++ct) {
      bf16x8 b = *(const bf16x8*)((const char*)&bt[0][0] + (ct*16 + l16) * 80 + lg * 16);
      acc2[0][ct] = __builtin_amdgcn_mfma_f32_16x16x32_bf16(a0, b, acc2[0][ct], 0, 0, 0);
      acc2[1][ct] = __builtin_amdgcn_mfma_f32_16x16x32_bf16(a1, b, acc2[1][ct], 0, 0, 0);
    }
  }
  // softmax over T=128 (row = 16-lane shfl group) + write probs f32
  #pragma unroll
  for (int rt = 0; rt < 2; ++rt) {
    #pragma unroll
    for (int reg = 0; reg < 4; ++reg) {
      float sv[8];
      float m = -1e30f;
      #pragma unroll
      for (int ct = 0; ct < 8; ++ct) {
        sv[ct] = acc2[rt][ct][reg] + dbv[ct];
        m = fmaxf(m, sv[ct]);
      }
      #pragma unroll
      for (int mm = 1; mm < 16; mm <<= 1) m = fmaxf(m, __shfl_xor(m, mm));
      float s = 0.f;
      #pragma unroll
      for (int ct = 0; ct < 8; ++ct) { sv[ct] = expf(sv[ct] - m); s += sv[ct]; }
      #pragma unroll
      for (int mm = 1; mm < 16; mm <<= 1) s += __shfl_xor(s, mm);
      float inv = 1.f / s;
      int row = w*32 + rt*16 + lg*4 + reg;
      #pragma unroll
      for (int ct = 0; ct < 8; ++ct)
        probs[(r0 + row) * (size_t)Tn + ct*16 + l16] = sv[ct] * inv;
    }
  }
}

// ================= launch ==================
extern "C" void kernel_launch(void* const* d_in, const int* in_sizes, int n_in,
                              void* d_out, int out_size, void* d_ws, size_t ws_size,
                              hipStream_t stream) {
  const float* q     = (const float*)d_in[0];
  const float* k     = (const float*)d_in[1];
  const float* v3    = (const float*)d_in[2];
  const float* proj  = (const float*)d_in[3];
  const float* enc_w = (const float*)d_in[4];
  const float* enc_b = (const float*)d_in[5];
  const float* ln_g  = (const float*)d_in[6];
  const float* ln_b  = (const float*)d_in[7];
  const float* dec_w = (const float*)d_in[8];
  const float* dec_b = (const float*)d_in[9];
  float* out = (float*)d_out;
  char* ws = (char*)d_ws;
  if (ws_size < WS_NEED) return;

  unsigned short* qf   = (unsigned short*)(ws + OFF_QF);
  unsigned short* kf   = (unsigned short*)(ws + OFF_KF);
  unsigned short* qk   = (unsigned short*)(ws + OFF_QK);
  float*          dden = (float*)(ws + OFF_D);
  float*          kpre = (float*)(ws + OFF_KPRE);
  unsigned short* ST   = (unsigned short*)(ws + OFF_S);
  unsigned short* ewt  = (unsigned short*)(ws + OFF_WT);             // aliases kf (dead after k_schunk)
  unsigned short* dwt  = (unsigned short*)(ws + OFF_WT + 49152);
  float* ctx   = out;
  float* probs = out + (size_t)BHn * Nn * E3n;

  k_features_mfma<<<dim3(BHn * Nn / 64, 2), 256, 0, stream>>>(q, k, proj, qf, kf);
  k_ksum        <<<dim3(BHn * NCn),     256, 0, stream>>>(kf, kpre);
  k_kprefix     <<<dim3(BHn),           256, 0, stream>>>(kpre);
  k_qk_mfma     <<<dim3(BHn * NCn),     256, 0, stream>>>(qf, kf, kpre, qk, dden);
  k_schunk_mfma <<<dim3(BHn * NCn, 3),  256, 0, stream>>>(kf, v3, ST);
  k_wt          <<<dim3(160),           256, 0, stream>>>(enc_w, dec_w, ewt, dwt);
  k_sprefix     <<<dim3(BHn * 51),      256, 0, stream>>>(ST);
  k_ctx_mfma    <<<dim3(BHn * NCn, 3),  256, 0, stream>>>(qf, qk, ST, v3, dden, ctx);
  k_pred_fused  <<<dim3(BHn * Nn / 128),256, 0, stream>>>(ctx, ewt, dwt, enc_b, ln_g,
                                                          ln_b, dec_b, probs);
}